// Round 2
// baseline (3596.011 us; speedup 1.0000x reference)
//
#include <hip/hip_runtime.h>
#include <math.h>

#define DD 384
#define HH 12
#define DKK 32
#define LL 6
#define FFF 1536
#define BB 64
#define SS 512
#define MROWS (BB*SS)   // 32768
#define TB 32           // scan time-tile
#define LDX 1152        // qkv row stride

typedef _Float16 f16;
typedef _Float16 half8 __attribute__((ext_vector_type(8)));
typedef _Float16 h2 __attribute__((ext_vector_type(2)));
typedef float f32x4 __attribute__((ext_vector_type(4)));
typedef float f32x2 __attribute__((ext_vector_type(2)));

__device__ __forceinline__ float sigmoidf_(float x){ return 1.0f/(1.0f+expf(-x)); }

__device__ __forceinline__ float h2f_lo(unsigned int u){
  union { unsigned short s; f16 h; } c; c.s = (unsigned short)(u & 0xffffu); return (float)c.h;
}
__device__ __forceinline__ float h2f_hi(unsigned int u){
  union { unsigned short s; f16 h; } c; c.s = (unsigned short)(u >> 16); return (float)c.h;
}

__device__ __forceinline__ void gl2lds16(const void* g, void* l){
  __builtin_amdgcn_global_load_lds((const __attribute__((address_space(1))) void*)g,
                                   (__attribute__((address_space(3))) void*)l, 16, 0, 0);
}

// ---------------- embedding + LN (writes fp32 x and f16 xh) ----------------
__global__ __launch_bounds__(256) void embed_ln_kernel(
    const int* __restrict__ ids, const float* __restrict__ we,
    const float* __restrict__ pe, const float* __restrict__ te,
    const float* __restrict__ w, const float* __restrict__ b,
    float* __restrict__ x, f16* __restrict__ xh)
{
  int wv = threadIdx.x >> 6, lane = threadIdx.x & 63;
  int row = blockIdx.x * 4 + wv;
  int s = row & (SS-1);
  int id = ids[row];
  const float* wep = we + (size_t)id * DD;
  const float* pep = pe + (size_t)s * DD;
  float vals[6]; float sum = 0.f;
  #pragma unroll
  for (int i=0;i<6;i++){ int d = lane + 64*i; vals[i] = wep[d] + pep[d] + te[d]; sum += vals[i]; }
  #pragma unroll
  for (int off=32; off>=1; off>>=1) sum += __shfl_xor(sum, off);
  float mean = sum * (1.0f/DD);
  float vs = 0.f;
  #pragma unroll
  for (int i=0;i<6;i++){ float dv = vals[i]-mean; vs += dv*dv; }
  #pragma unroll
  for (int off=32; off>=1; off>>=1) vs += __shfl_xor(vs, off);
  float inv = rsqrtf(vs*(1.0f/DD) + 1e-12f);
  float* xr = x + (size_t)row*DD;
  f16* xhr = xh + (size_t)row*DD;
  #pragma unroll
  for (int i=0;i<6;i++){ int d = lane + 64*i; float o = (vals[i]-mean)*inv*w[d] + b[d]; xr[d]=o; xhr[d]=(f16)o; }
}

// ---------------- x = LN(x + y); y f32 (YH=0) or f16 (YH=1), stride ldy ----------------
template<int YH>
__global__ __launch_bounds__(256) void add_ln_kernel(
    float* __restrict__ x, f16* __restrict__ xh, const void* __restrict__ yp,
    const float* __restrict__ w, const float* __restrict__ b, int row0, int ldy)
{
  int wv = threadIdx.x >> 6, lane = threadIdx.x & 63;
  int rrel = blockIdx.x * 4 + wv;
  int row = row0 + rrel;
  float* xr = x + (size_t)row*DD;
  f16* xhr = xh + (size_t)row*DD;
  float vals[6]; float sum = 0.f;
  #pragma unroll
  for (int i=0;i<6;i++){
    int d = lane + 64*i;
    float yv;
    if (YH) yv = (float)((const f16*)yp)[(size_t)rrel*ldy + d];
    else    yv = ((const float*)yp)[(size_t)rrel*ldy + d];
    vals[i] = xr[d] + yv; sum += vals[i];
  }
  #pragma unroll
  for (int off=32; off>=1; off>>=1) sum += __shfl_xor(sum, off);
  float mean = sum * (1.0f/DD);
  float vs = 0.f;
  #pragma unroll
  for (int i=0;i<6;i++){ float dv = vals[i]-mean; vs += dv*dv; }
  #pragma unroll
  for (int off=32; off>=1; off>>=1) vs += __shfl_xor(vs, off);
  float inv = rsqrtf(vs*(1.0f/DD) + 1e-12f);
  #pragma unroll
  for (int i=0;i<6;i++){ int d = lane + 64*i; float o = (vals[i]-mean)*inv*w[d] + b[d]; xr[d]=o; xhr[d]=(f16)o; }
}

// ---------------- bias pack: [bq;bk;bv] per layer -> 1152 each ----------------
__global__ __launch_bounds__(256) void biaspack_kernel(
    const float* __restrict__ bq, const float* __restrict__ bk, const float* __restrict__ bv,
    float* __restrict__ dst)
{
  int i = blockIdx.x*256 + threadIdx.x;   // 6912 total
  if (i >= LL*LDX) return;
  int l = i / LDX, r = i - l*LDX;
  float v;
  if (r < 384) v = bq[l*DD + r];
  else if (r < 768) v = bk[l*DD + r-384];
  else v = bv[l*DD + r-768];
  dst[i] = v;
}

// ---------------- weight transpose + f32->f16, ALL layers in one dispatch ----------------
__global__ __launch_bounds__(256) void wtrans_kernel(
  const float* __restrict__ Wq, const float* __restrict__ Wk, const float* __restrict__ Wv,
  const float* __restrict__ Wo, const float* __restrict__ W1, const float* __restrict__ W2,
  f16* __restrict__ Wt)
{
  __shared__ float T[32][33];
  int l = blockIdx.x / 1728, bidx = blockIdx.x % 1728;
  const float* src; f16* dst; int K, N, tile;
  if (bidx < 576){ int m = bidx/144; tile = bidx - m*144; K=384; N=384;
    const float* w4[4] = {Wq + (size_t)l*147456, Wk + (size_t)l*147456,
                          Wv + (size_t)l*147456, Wo + (size_t)l*147456};
    src = w4[m]; dst = Wt + (size_t)l*1769472 + m*147456; }
  else if (bidx < 1152){ tile = bidx-576; K=384; N=1536;
    src = W1 + (size_t)l*589824; dst = Wt + (size_t)l*1769472 + 589824; }
  else { tile = bidx-1152; K=1536; N=384;
    src = W2 + (size_t)l*589824; dst = Wt + (size_t)l*1769472 + 1179648; }
  int tN = N>>5;
  int tk = tile / tN, tn = tile - tk*tN;
  int k0 = tk<<5, n0 = tn<<5;
  int r = threadIdx.x >> 3, c4 = (threadIdx.x & 7) << 2;
  float4 vv = *(const float4*)(src + (size_t)(k0+r)*N + n0 + c4);
  T[r][c4+0]=vv.x; T[r][c4+1]=vv.y; T[r][c4+2]=vv.z; T[r][c4+3]=vv.w;
  __syncthreads();
  f16* dp = dst + (size_t)(n0+r)*K + k0 + c4;
  #pragma unroll
  for (int j=0;j<4;j++) dp[j] = (f16)T[c4+j][r];
}

// ---------------- f16 MFMA GEMM, BK=64: C = act(A @ BT^T + bias), strided A/C ----------------
template<int ACT, int OUT16>
__global__ __launch_bounds__(256) void gemm_f16(
    const f16* __restrict__ A, const f16* __restrict__ BT,
    const float* __restrict__ bias, float* __restrict__ Cf, f16* __restrict__ Ch,
    int M, int N, int K, int lda, int ldc)
{
  __shared__ __align__(16) f16 As0[128*32];
  __shared__ __align__(16) f16 As1[128*32];
  __shared__ __align__(16) f16 Bs0[128*32];
  __shared__ __align__(16) f16 Bs1[128*32];
  int tid = threadIdx.x, lane = tid & 63, wave = tid >> 6;
  int wm = wave >> 1, wn = wave & 1;
  int n0 = blockIdx.x * 128, m0 = blockIdx.y * 128;
  f32x4 acc[4][4] = {};
  int seg0 = wave*2048 + lane*16;
  int ar = lane & 15, kq = (lane >> 4) * 8;

  for (int k0=0; k0<K; k0+=64){
    #pragma unroll
    for (int i=0;i<2;i++){
      int seg = seg0 + i*1024;
      int e = seg >> 1; int row = e >> 5; int kk = e & 31;
      const f16* ap = A  + (size_t)(m0+row)*lda + k0 + kk;
      const f16* bp = BT + (size_t)(n0+row)*K   + k0 + kk;
      gl2lds16(ap,      (char*)As0 + seg);
      gl2lds16(ap + 32, (char*)As1 + seg);
      gl2lds16(bp,      (char*)Bs0 + seg);
      gl2lds16(bp + 32, (char*)Bs1 + seg);
    }
    __syncthreads();
    {
      half8 af[4], bf[4];
      #pragma unroll
      for (int mi=0;mi<4;mi++) af[mi] = *(const half8*)&As0[(wm*64 + mi*16 + ar)*32 + kq];
      #pragma unroll
      for (int ni=0;ni<4;ni++) bf[ni] = *(const half8*)&Bs0[(wn*64 + ni*16 + ar)*32 + kq];
      #pragma unroll
      for (int mi=0;mi<4;mi++)
        #pragma unroll
        for (int ni=0;ni<4;ni++)
          acc[mi][ni] = __builtin_amdgcn_mfma_f32_16x16x32_f16(af[mi], bf[ni], acc[mi][ni], 0, 0, 0);
    }
    {
      half8 af[4], bf[4];
      #pragma unroll
      for (int mi=0;mi<4;mi++) af[mi] = *(const half8*)&As1[(wm*64 + mi*16 + ar)*32 + kq];
      #pragma unroll
      for (int ni=0;ni<4;ni++) bf[ni] = *(const half8*)&Bs1[(wn*64 + ni*16 + ar)*32 + kq];
      #pragma unroll
      for (int mi=0;mi<4;mi++)
        #pragma unroll
        for (int ni=0;ni<4;ni++)
          acc[mi][ni] = __builtin_amdgcn_mfma_f32_16x16x32_f16(af[mi], bf[ni], acc[mi][ni], 0, 0, 0);
    }
    __syncthreads();
  }
  int rb = (lane >> 4) * 4, cb = lane & 15;
  #pragma unroll
  for (int ni=0;ni<4;ni++){
    int cn = n0 + wn*64 + ni*16 + cb;
    float bz = bias[cn];
    #pragma unroll
    for (int mi=0;mi<4;mi++){
      int rm = m0 + wm*64 + mi*16 + rb;
      #pragma unroll
      for (int r=0;r<4;r++){
        float v = acc[mi][ni][r] + bz;
        if (ACT==1) v = 0.5f*v*(1.0f+erff(v*0.70710678118f));
        if (OUT16) Ch[(size_t)(rm+r)*ldc + cn] = (f16)v;
        else       Cf[(size_t)(rm+r)*ldc + cn] = v;
      }
    }
  }
}

// ---------------- beta/g projections ----------------
__global__ __launch_bounds__(256) void betag_kernel(
    const float* __restrict__ x, const float* __restrict__ Wb, const float* __restrict__ bb,
    const float* __restrict__ Wg, const float* __restrict__ bg,
    const int* __restrict__ mask, float* __restrict__ beta, float* __restrict__ g)
{
  __shared__ float Ws[384*25];
  for (int idx = threadIdx.x; idx < 384*12; idx += 256){
    int k = idx/12, j = idx - k*12;
    Ws[k*25+j]    = Wb[idx];
    Ws[k*25+12+j] = Wg[idx];
  }
  __syncthreads();
  int wv = threadIdx.x>>6, lane = threadIdx.x&63;
  int row = blockIdx.x*4 + wv;
  const float* xr = x + (size_t)row*DD;
  float accb[12], accg[12];
  #pragma unroll
  for (int j=0;j<12;j++){ accb[j]=0.f; accg[j]=0.f; }
  #pragma unroll
  for (int i=0;i<6;i++){
    int k = lane + 64*i;
    float xv = xr[k];
    const float* wr = &Ws[k*25];
    #pragma unroll
    for (int j=0;j<12;j++){ accb[j] += xv*wr[j]; accg[j] += xv*wr[12+j]; }
  }
  #pragma unroll
  for (int j=0;j<12;j++){
    #pragma unroll
    for (int off=32; off>=1; off>>=1){
      accb[j]+=__shfl_xor(accb[j],off);
      accg[j]+=__shfl_xor(accg[j],off);
    }
  }
  if (lane==0){
    float mk = (float)mask[row];
    #pragma unroll
    for (int j=0;j<12;j++){
      beta[(size_t)row*HH + j] = sigmoidf_(accb[j]+bb[j]) * mk;
      g[(size_t)row*HH + j]    = sigmoidf_(accg[j]+bg[j]);
    }
  }
}

// ---------------- DeltaNet dual-state scan (R11: 1 wave, k-half lane split) ----------------
// Evidence: R6 (1 wave, 16 bcast b128/step) = 718 cy/step; R10 (4 waves, same LDS count,
// more issue + chain shfl + barriers) = 866 cy/step. Model: per-CU broadcast-ds_read stream
// is the floor. R11 keeps R6's single-wave barrier-free step loop but maps
// lane = (khalf, col): each lane holds BOTH states for 16 of 32 k-entries (same 32 regs),
// reads only half of each k/q row -> 8 b128/step (halved). k-half partials combine with
// __shfl_xor(p,32) (v_permlane64_b32, VALU) - 3 per step. Output: fast written by khalf0
// lanes, slow by khalf1 lanes, one exchange shuffle. COMBINE/staging unchanged.
__global__ __launch_bounds__(64) void scan_kernel(
  f16* qkv,
  const float* __restrict__ bp, const float* __restrict__ gp,
  const float* __restrict__ flp, const float* __restrict__ slp)
{
  __shared__ float Kf[2][TB][32];
  __shared__ float Qf[2][TB][32];
  __shared__ float Vf[2][TB][32];
  __shared__ float Bg[2][2][TB];
  __shared__ float Of[TB][64];
  int blk = blockIdx.x;
  int b = blk / HH, h = blk - b*HH;
  int lane = threadIdx.x;
  int col  = lane & 31;
  int khalf = lane >> 5;          // 0: k[0:16), 1: k[16:32)
  int kq0 = khalf*4;              // float4 index into the 8-float4 row
  int ofs = khalf*32 + col;       // Of slot: fast at col, slow at col+32

  float afv = sigmoidf_(flp[h]);
  float asv = sigmoidf_(slp[h]);
  f32x2 af2 = {afv, afv}, as2 = {asv, asv};
  f32x2 Sf[8], Ss[8];
  #pragma unroll
  for (int j=0;j<8;j++){ Sf[j] = (f32x2){0.f,0.f}; Ss[j] = (f32x2){0.f,0.f}; }

  size_t base = ((size_t)b*SS)*LDX + (size_t)h*DKK;
  f16* qb = qkv + base;
  const f16* kb = qkv + base + 384;
  const f16* vb = qkv + base + 768;
  const float* bbp = bp + ((size_t)b*SS)*HH + h;
  const float* gbp = gp + ((size_t)b*SS)*HH + h;

  int st0 = lane >> 2, part = lane & 3;
  uint4 kv[2], qv[2], vv[2]; float bgv;

  #define LOADG(T0) do {                                                       \
    _Pragma("unroll")                                                          \
    for (int r=0;r<2;r++){                                                     \
      int st = (T0) + r*16 + st0;                                              \
      size_t off = (size_t)st*LDX + part*8;                                    \
      kv[r] = *(const uint4*)(kb + off);                                       \
      qv[r] = *(const uint4*)(qb + off);                                       \
      vv[r] = *(const uint4*)(vb + off);                                       \
    }                                                                          \
    int tb_ = (T0) + (lane & 31);                                              \
    bgv = (lane < 32) ? bbp[(size_t)tb_*HH] : gbp[(size_t)tb_*HH];             \
  } while(0)

  #define STAGE(BUF) do {                                                      \
    _Pragma("unroll")                                                          \
    for (int r=0;r<2;r++){                                                     \
      int s = r*16 + st0;                                                      \
      float kf[8], qf[8], vf[8];                                               \
      kf[0]=h2f_lo(kv[r].x); kf[1]=h2f_hi(kv[r].x); kf[2]=h2f_lo(kv[r].y);     \
      kf[3]=h2f_hi(kv[r].y); kf[4]=h2f_lo(kv[r].z); kf[5]=h2f_hi(kv[r].z);     \
      kf[6]=h2f_lo(kv[r].w); kf[7]=h2f_hi(kv[r].w);                            \
      qf[0]=h2f_lo(qv[r].x); qf[1]=h2f_hi(qv[r].x); qf[2]=h2f_lo(qv[r].y);     \
      qf[3]=h2f_hi(qv[r].y); qf[4]=h2f_lo(qv[r].z); qf[5]=h2f_hi(qv[r].z);     \
      qf[6]=h2f_lo(qv[r].w); qf[7]=h2f_hi(qv[r].w);                            \
      vf[0]=h2f_lo(vv[r].x); vf[1]=h2f_hi(vv[r].x); vf[2]=h2f_lo(vv[r].y);     \
      vf[3]=h2f_hi(vv[r].y); vf[4]=h2f_lo(vv[r].z); vf[5]=h2f_hi(vv[r].z);     \
      vf[6]=h2f_lo(vv[r].w); vf[7]=h2f_hi(vv[r].w);                            \
      float ss = 0.f;                                                          \
      _Pragma("unroll")                                                        \
      for (int i=0;i<8;i++) ss += kf[i]*kf[i];                                 \
      ss += __shfl_xor(ss, 1); ss += __shfl_xor(ss, 2);                        \
      float sc = 1.0f/(sqrtf(ss)+1e-6f);                                       \
      float4 t;                                                                \
      t.x=kf[0]*sc; t.y=kf[1]*sc; t.z=kf[2]*sc; t.w=kf[3]*sc;                  \
      *(float4*)&Kf[BUF][s][part*8] = t;                                       \
      t.x=kf[4]*sc; t.y=kf[5]*sc; t.z=kf[6]*sc; t.w=kf[7]*sc;                  \
      *(float4*)&Kf[BUF][s][part*8+4] = t;                                     \
      t.x=qf[0]; t.y=qf[1]; t.z=qf[2]; t.w=qf[3];                              \
      *(float4*)&Qf[BUF][s][part*8] = t;                                       \
      t.x=qf[4]; t.y=qf[5]; t.z=qf[6]; t.w=qf[7];                              \
      *(float4*)&Qf[BUF][s][part*8+4] = t;                                     \
      t.x=vf[0]; t.y=vf[1]; t.z=vf[2]; t.w=vf[3];                              \
      *(float4*)&Vf[BUF][s][part*8] = t;                                       \
      t.x=vf[4]; t.y=vf[5]; t.z=vf[6]; t.w=vf[7];                              \
      *(float4*)&Vf[BUF][s][part*8+4] = t;                                     \
    }                                                                          \
    Bg[BUF][lane>>5][lane&31] = bgv;                                           \
  } while(0)

  #define LDSTEP(BUF,S,KR,QR,VT,BT) do {                                       \
    const float4* k4_ = (const float4*)&Kf[BUF][S][0];                         \
    const float4* q4_ = (const float4*)&Qf[BUF][S][0];                         \
    KR[0]=k4_[kq0]; KR[1]=k4_[kq0+1]; KR[2]=k4_[kq0+2]; KR[3]=k4_[kq0+3];      \
    QR[0]=q4_[kq0]; QR[1]=q4_[kq0+1]; QR[2]=q4_[kq0+2]; QR[3]=q4_[kq0+3];      \
    VT = Vf[BUF][S][col]; BT = Bg[BUF][0][S];                                  \
  } while(0)

  #define STEP(KR,QR,VT,BT,S) do {                                            \
    const f32x2* k2_ = (const f32x2*)KR;                                       \
    const f32x2* q2_ = (const f32x2*)QR;                                       \
    f32x2 fA = Sf[0]*k2_[0]; f32x2 fB = Sf[1]*k2_[1];                          \
    f32x2 sA = Ss[0]*k2_[0]; f32x2 sB = Ss[1]*k2_[1];                          \
    fA += Sf[2]*k2_[2]; fB += Sf[3]*k2_[3];                                    \
    sA += Ss[2]*k2_[2]; sB += Ss[3]*k2_[3];                                    \
    fA += Sf[4]*k2_[4]; fB += Sf[5]*k2_[5];                                    \
    sA += Ss[4]*k2_[4]; sB += Ss[5]*k2_[5];                                    \
    fA += Sf[6]*k2_[6]; fB += Sf[7]*k2_[7];                                    \
    sA += Ss[6]*k2_[6]; sB += Ss[7]*k2_[7];                                    \
    f32x2 fT = fA + fB; f32x2 sT = sA + sB;                                    \
    float pf = fT.x + fT.y;                                                    \
    float ps = sT.x + sT.y;                                                    \
    float rf = pf + __shfl_xor(pf, 32);                                        \
    float rs = ps + __shfl_xor(ps, 32);                                        \
    float cf_ = (BT)*((VT) - rf);                                              \
    float cs_ = (BT)*((VT) - rs);                                              \
    f32x2 cf2 = {cf_, cf_}, cs2 = {cs_, cs_};                                  \
    _Pragma("unroll")                                                          \
    for (int j=0;j<8;j++){                                                     \
      Sf[j] = af2*Sf[j] + cf2*k2_[j];                                          \
      Ss[j] = as2*Ss[j] + cs2*k2_[j];                                          \
    }                                                                          \
    f32x2 oA = Sf[0]*q2_[0]; f32x2 oB = Sf[1]*q2_[1];                          \
    f32x2 uA = Ss[0]*q2_[0]; f32x2 uB = Ss[1]*q2_[1];                          \
    oA += Sf[2]*q2_[2]; oB += Sf[3]*q2_[3];                                    \
    uA += Ss[2]*q2_[2]; uB += Ss[3]*q2_[3];                                    \
    oA += Sf[4]*q2_[4]; oB += Sf[5]*q2_[5];                                    \
    uA += Ss[4]*q2_[4]; uB += Ss[5]*q2_[5];                                    \
    oA += Sf[6]*q2_[6]; oB += Sf[7]*q2_[7];                                    \
    uA += Ss[6]*q2_[6]; uB += Ss[7]*q2_[7];                                    \
    f32x2 oT = oA + oB; f32x2 uT = uA + uB;                                    \
    float of_p = oT.x + oT.y;                                                  \
    float os_p = uT.x + uT.y;                                                  \
    float send_ = khalf ? of_p : os_p;                                         \
    float recv_ = __shfl_xor(send_, 32);                                       \
    float o_ = (khalf ? os_p : of_p) + recv_;                                  \
    Of[S][ofs] = o_;                                                           \
  } while(0)

  #define COMBINE(BUF,T0) do {                                                 \
    _Pragma("unroll")                                                          \
    for (int i=0;i<16;i++){                                                    \
      int idx = i*64 + lane;                                                   \
      int s_ = idx >> 5, c_ = idx & 31;                                        \
      float fv = Of[s_][c_];                                                   \
      float sv = Of[s_][c_+32];                                                \
      float gv = Bg[BUF][1][s_];                                               \
      qb[(size_t)((T0)+s_)*LDX + c_] = (f16)(gv*fv + (1.0f-gv)*sv);            \
    }                                                                          \
  } while(0)

  LOADG(0);
  STAGE(0);
  __syncthreads();

  float4 kA[4], qA[4], kB[4], qB[4];
  float vA, bA, vB, bB;

  for (int tile=0; tile<SS/TB; tile++){
    int buf = tile & 1;
    if (tile < SS/TB-1) LOADG((tile+1)*TB);
    LDSTEP(buf, 0, kA, qA, vA, bA);
    #pragma unroll
    for (int s=0; s<TB; s+=2){
      if (s+1 < TB) LDSTEP(buf, s+1, kB, qB, vB, bB);
      STEP(kA, qA, vA, bA, s);
      if (s+2 < TB) LDSTEP(buf, s+2, kA, qA, vA, bA);
      STEP(kB, qB, vB, bB, s+1);
    }
    if (tile < SS/TB-1) STAGE(1-buf);
    COMBINE(buf, tile*TB);
    __syncthreads();
  }
  #undef LOADG
  #undef STAGE
  #undef LDSTEP
  #undef STEP
  #undef COMBINE
}

// ---------------- masked mean-pool + L2 normalize ----------------
__global__ __launch_bounds__(384) void pool_kernel(
    const float* __restrict__ x, const int* __restrict__ mask, float* __restrict__ out)
{
  __shared__ float red[384];
  __shared__ float tot;
  int b = blockIdx.x, d = threadIdx.x;
  const float* xb = x + (size_t)b*SS*DD;
  const int* mb = mask + b*SS;
  float s=0.f, sm=0.f;
  for (int t=0;t<SS;t++){ float m=(float)mb[t]; s += xb[(size_t)t*DD+d]*m; sm += m; }
  float emb = s / fmaxf(sm, 1e-9f);
  red[d] = emb*emb;
  __syncthreads();
  for (int off=192; off>=3; off>>=1){
    if (d < off) red[d] += red[d+off];
    __syncthreads();
  }
  if (d==0) tot = red[0]+red[1]+red[2];
  __syncthreads();
  out[(size_t)b*DD + d] = emb * rsqrtf(tot);
}

extern "C" void kernel_launch(void* const* d_in, const int* in_sizes, int n_in,
                              void* d_out, int out_size, void* d_ws, size_t ws_size,
                              hipStream_t stream)
{
  const int*   ids  = (const int*)d_in[0];
  const int*   amask= (const int*)d_in[1];
  const float* we   = (const float*)d_in[2];
  const float* pe   = (const float*)d_in[3];
  const float* te   = (const float*)d_in[4];
  const float* elnw = (const float*)d_in[5];
  const float* elnb = (const float*)d_in[6];
  const float* Wq   = (const float*)d_in[7];
  const float* bq   = (const float*)d_in[8];
  const float* Wk   = (const float*)d_in[9];
  const float* bk   = (const float*)d_in[10];
  const float* Wv   = (const float*)d_in[11];
  const float* bv   = (const float*)d_in[12];
  const float* Wb   = (const float*)d_in[13];
  const float* bb   = (const float*)d_in[14];
  const float* Wg   = (const float*)d_in[15];
  const float* bgp  = (const float*)d_in[16];
  const float* Wo   = (const float*)d_in[17];
  const float* bo   = (const float*)d_in[18];
  const float* fl   = (const float*)d_in[19];
  const float* sl   = (const float*)d_in[20];
  const float* alnw = (const float*)d_in[21];
  const float* alnb = (const float*)d_in[22];
  const float* W1   = (const float*)d_in[23];
  const float* b1   = (const float*)d_in[24];
  const float* W2   = (const float*)d_in[25];
  const float* b2   = (const float*)d_in[26];
  const float* flnw = (const float*)d_in[27];
  const float* flnb = (const float*)d_in[28];
  float* out = (float*)d_out;
  float* w = (float*)d_ws;

  // workspace (float slots), total 49,355,520 f = 197.4 MB
  float* x    = w;                      // 12,582,912 f
  f16*  xh   = (f16*)(w + 12582912);    // 12,582,912 h
  f16*  qkvh = (f16*)(w + 18874368);    // 37,748,736 h  [row][1152]
  float* f2   = w + 37748736;           //  6,291,456 f region
  f16*  f2h  = (f16*)f2;                // FFN2 out as f16 (chunk 16384x384)
  float* beta = f2 + 3145728;           //    393,216 f (beyond f2h chunk use)
  float* gbuf = beta + 393216;          //    393,216 f
  f16*  wt   = (f16*)(w + 44040192);    // 10,616,832 h (all 6 layers)
  float* bqkv = w + 49348608;           //      6,912 f
  f16*  hbf  = qkvh;                    // FFN hidden chunk 16384x1536 h overlays qkv

  embed_ln_kernel<<<MROWS/4, 256, 0, stream>>>(ids, we, pe, te, elnw, elnb, x, xh);
  biaspack_kernel<<<27,256,0,stream>>>(bq, bk, bv, bqkv);
  wtrans_kernel<<<LL*1728,256,0,stream>>>(Wq, Wk, Wv, Wo, W1, W2, wt);

  for (int l=0;l<LL;l++){
    f16* wl = wt + (size_t)l*1769472;

    // fused QKV: [32768 x 1152] = xh @ [Wq|Wk|Wv]^T
    gemm_f16<0,1><<<dim3(9,256),256,0,stream>>>(xh, wl, bqkv + l*LDX, nullptr, qkvh,
                                                MROWS, LDX, DD, DD, LDX);

    betag_kernel<<<MROWS/4,256,0,stream>>>(x, Wb + (size_t)l*DD*HH, bb + l*HH,
                                           Wg + (size_t)l*DD*HH, bgp + l*HH,
                                           amask, beta, gbuf);
    scan_kernel<<<BB*HH,64,0,stream>>>(qkvh, beta, gbuf, fl + l*HH, sl + l*HH);

    // o-proj full-M: A = attn-out = qkv[:,0:384] (lda=1152), C(f16) -> dead k-slot qkv[:,384:768]
    gemm_f16<0,1><<<dim3(3,256),256,0,stream>>>(qkvh, wl+442368, bo+l*DD, nullptr,
                                                qkvh + 384, MROWS, DD, DD, LDX, LDX);
    add_ln_kernel<1><<<MROWS/4,256,0,stream>>>(x, xh, qkvh + 384, alnw+l*DD, alnb+l*DD, 0, LDX);

    // FFN in 2 row-chunks of 16384 (hidden overlays qkv); FFN2 out f16
    for (int c=0;c<2;c++){
      gemm_f16<1,1><<<dim3(12,128),256,0,stream>>>(xh + (size_t)c*16384*DD, wl+589824,
                                                   b1+l*FFF, nullptr, hbf, 16384, FFF, DD, DD, FFF);
      gemm_f16<0,1><<<dim3(3,128),256,0,stream>>>(hbf, wl+1179648, b2+l*DD, nullptr, f2h,
                                                  16384, DD, FFF, FFF, DD);
      add_ln_kernel<1><<<4096,256,0,stream>>>(x, xh, f2h, flnw+l*DD, flnb+l*DD, c*16384, DD);
    }
  }

  pool_kernel<<<BB,384,0,stream>>>(x, amask, out);
}

// Round 3
// 3503.699 us; speedup vs baseline: 1.0263x; 1.0263x over previous
//
#include <hip/hip_runtime.h>
#include <math.h>

#define DD 384
#define HH 12
#define DKK 32
#define LL 6
#define FFF 1536
#define BB 64
#define SS 512
#define MROWS (BB*SS)   // 32768
#define TB 32           // scan time-tile
#define LDX 1152        // qkv row stride

typedef _Float16 f16;
typedef _Float16 half8 __attribute__((ext_vector_type(8)));
typedef _Float16 h2 __attribute__((ext_vector_type(2)));
typedef float f32x4 __attribute__((ext_vector_type(4)));
typedef float f32x2 __attribute__((ext_vector_type(2)));

__device__ __forceinline__ float sigmoidf_(float x){ return 1.0f/(1.0f+expf(-x)); }

__device__ __forceinline__ float h2f_lo(unsigned int u){
  union { unsigned short s; f16 h; } c; c.s = (unsigned short)(u & 0xffffu); return (float)c.h;
}
__device__ __forceinline__ float h2f_hi(unsigned int u){
  union { unsigned short s; f16 h; } c; c.s = (unsigned short)(u >> 16); return (float)c.h;
}

__device__ __forceinline__ void gl2lds16(const void* g, void* l){
  __builtin_amdgcn_global_load_lds((const __attribute__((address_space(1))) void*)g,
                                   (__attribute__((address_space(3))) void*)l, 16, 0, 0);
}

// ---------------- embedding + LN (writes fp32 x and f16 xh) ----------------
__global__ __launch_bounds__(256) void embed_ln_kernel(
    const int* __restrict__ ids, const float* __restrict__ we,
    const float* __restrict__ pe, const float* __restrict__ te,
    const float* __restrict__ w, const float* __restrict__ b,
    float* __restrict__ x, f16* __restrict__ xh)
{
  int wv = threadIdx.x >> 6, lane = threadIdx.x & 63;
  int row = blockIdx.x * 4 + wv;
  int s = row & (SS-1);
  int id = ids[row];
  const float* wep = we + (size_t)id * DD;
  const float* pep = pe + (size_t)s * DD;
  float vals[6]; float sum = 0.f;
  #pragma unroll
  for (int i=0;i<6;i++){ int d = lane + 64*i; vals[i] = wep[d] + pep[d] + te[d]; sum += vals[i]; }
  #pragma unroll
  for (int off=32; off>=1; off>>=1) sum += __shfl_xor(sum, off);
  float mean = sum * (1.0f/DD);
  float vs = 0.f;
  #pragma unroll
  for (int i=0;i<6;i++){ float dv = vals[i]-mean; vs += dv*dv; }
  #pragma unroll
  for (int off=32; off>=1; off>>=1) vs += __shfl_xor(vs, off);
  float inv = rsqrtf(vs*(1.0f/DD) + 1e-12f);
  float* xr = x + (size_t)row*DD;
  f16* xhr = xh + (size_t)row*DD;
  #pragma unroll
  for (int i=0;i<6;i++){ int d = lane + 64*i; float o = (vals[i]-mean)*inv*w[d] + b[d]; xr[d]=o; xhr[d]=(f16)o; }
}

// ---------------- x = LN(x + y); y f32 (YH=0) or f16 (YH=1), stride ldy ----------------
template<int YH>
__global__ __launch_bounds__(256) void add_ln_kernel(
    float* __restrict__ x, f16* __restrict__ xh, const void* __restrict__ yp,
    const float* __restrict__ w, const float* __restrict__ b, int row0, int ldy)
{
  int wv = threadIdx.x >> 6, lane = threadIdx.x & 63;
  int rrel = blockIdx.x * 4 + wv;
  int row = row0 + rrel;
  float* xr = x + (size_t)row*DD;
  f16* xhr = xh + (size_t)row*DD;
  float vals[6]; float sum = 0.f;
  #pragma unroll
  for (int i=0;i<6;i++){
    int d = lane + 64*i;
    float yv;
    if (YH) yv = (float)((const f16*)yp)[(size_t)rrel*ldy + d];
    else    yv = ((const float*)yp)[(size_t)rrel*ldy + d];
    vals[i] = xr[d] + yv; sum += vals[i];
  }
  #pragma unroll
  for (int off=32; off>=1; off>>=1) sum += __shfl_xor(sum, off);
  float mean = sum * (1.0f/DD);
  float vs = 0.f;
  #pragma unroll
  for (int i=0;i<6;i++){ float dv = vals[i]-mean; vs += dv*dv; }
  #pragma unroll
  for (int off=32; off>=1; off>>=1) vs += __shfl_xor(vs, off);
  float inv = rsqrtf(vs*(1.0f/DD) + 1e-12f);
  #pragma unroll
  for (int i=0;i<6;i++){ int d = lane + 64*i; float o = (vals[i]-mean)*inv*w[d] + b[d]; xr[d]=o; xhr[d]=(f16)o; }
}

// ---------------- bias pack: [bq;bk;bv] per layer -> 1152 each ----------------
__global__ __launch_bounds__(256) void biaspack_kernel(
    const float* __restrict__ bq, const float* __restrict__ bk, const float* __restrict__ bv,
    float* __restrict__ dst)
{
  int i = blockIdx.x*256 + threadIdx.x;   // 6912 total
  if (i >= LL*LDX) return;
  int l = i / LDX, r = i - l*LDX;
  float v;
  if (r < 384) v = bq[l*DD + r];
  else if (r < 768) v = bk[l*DD + r-384];
  else v = bv[l*DD + r-768];
  dst[i] = v;
}

// ---------------- weight transpose + f32->f16, ALL layers in one dispatch ----------------
__global__ __launch_bounds__(256) void wtrans_kernel(
  const float* __restrict__ Wq, const float* __restrict__ Wk, const float* __restrict__ Wv,
  const float* __restrict__ Wo, const float* __restrict__ W1, const float* __restrict__ W2,
  f16* __restrict__ Wt)
{
  __shared__ float T[32][33];
  int l = blockIdx.x / 1728, bidx = blockIdx.x % 1728;
  const float* src; f16* dst; int K, N, tile;
  if (bidx < 576){ int m = bidx/144; tile = bidx - m*144; K=384; N=384;
    const float* w4[4] = {Wq + (size_t)l*147456, Wk + (size_t)l*147456,
                          Wv + (size_t)l*147456, Wo + (size_t)l*147456};
    src = w4[m]; dst = Wt + (size_t)l*1769472 + m*147456; }
  else if (bidx < 1152){ tile = bidx-576; K=384; N=1536;
    src = W1 + (size_t)l*589824; dst = Wt + (size_t)l*1769472 + 589824; }
  else { tile = bidx-1152; K=1536; N=384;
    src = W2 + (size_t)l*589824; dst = Wt + (size_t)l*1769472 + 1179648; }
  int tN = N>>5;
  int tk = tile / tN, tn = tile - tk*tN;
  int k0 = tk<<5, n0 = tn<<5;
  int r = threadIdx.x >> 3, c4 = (threadIdx.x & 7) << 2;
  float4 vv = *(const float4*)(src + (size_t)(k0+r)*N + n0 + c4);
  T[r][c4+0]=vv.x; T[r][c4+1]=vv.y; T[r][c4+2]=vv.z; T[r][c4+3]=vv.w;
  __syncthreads();
  f16* dp = dst + (size_t)(n0+r)*K + k0 + c4;
  #pragma unroll
  for (int j=0;j<4;j++) dp[j] = (f16)T[c4+j][r];
}

// ---------------- f16 MFMA GEMM, BK=64: C = act(A @ BT^T + bias), strided A/C ----------------
template<int ACT, int OUT16>
__global__ __launch_bounds__(256) void gemm_f16(
    const f16* __restrict__ A, const f16* __restrict__ BT,
    const float* __restrict__ bias, float* __restrict__ Cf, f16* __restrict__ Ch,
    int M, int N, int K, int lda, int ldc)
{
  __shared__ __align__(16) f16 As0[128*32];
  __shared__ __align__(16) f16 As1[128*32];
  __shared__ __align__(16) f16 Bs0[128*32];
  __shared__ __align__(16) f16 Bs1[128*32];
  int tid = threadIdx.x, lane = tid & 63, wave = tid >> 6;
  int wm = wave >> 1, wn = wave & 1;
  int n0 = blockIdx.x * 128, m0 = blockIdx.y * 128;
  f32x4 acc[4][4] = {};
  int seg0 = wave*2048 + lane*16;
  int ar = lane & 15, kq = (lane >> 4) * 8;

  for (int k0=0; k0<K; k0+=64){
    #pragma unroll
    for (int i=0;i<2;i++){
      int seg = seg0 + i*1024;
      int e = seg >> 1; int row = e >> 5; int kk = e & 31;
      const f16* ap = A  + (size_t)(m0+row)*lda + k0 + kk;
      const f16* bp = BT + (size_t)(n0+row)*K   + k0 + kk;
      gl2lds16(ap,      (char*)As0 + seg);
      gl2lds16(ap + 32, (char*)As1 + seg);
      gl2lds16(bp,      (char*)Bs0 + seg);
      gl2lds16(bp + 32, (char*)Bs1 + seg);
    }
    __syncthreads();
    {
      half8 af[4], bf[4];
      #pragma unroll
      for (int mi=0;mi<4;mi++) af[mi] = *(const half8*)&As0[(wm*64 + mi*16 + ar)*32 + kq];
      #pragma unroll
      for (int ni=0;ni<4;ni++) bf[ni] = *(const half8*)&Bs0[(wn*64 + ni*16 + ar)*32 + kq];
      #pragma unroll
      for (int mi=0;mi<4;mi++)
        #pragma unroll
        for (int ni=0;ni<4;ni++)
          acc[mi][ni] = __builtin_amdgcn_mfma_f32_16x16x32_f16(af[mi], bf[ni], acc[mi][ni], 0, 0, 0);
    }
    {
      half8 af[4], bf[4];
      #pragma unroll
      for (int mi=0;mi<4;mi++) af[mi] = *(const half8*)&As1[(wm*64 + mi*16 + ar)*32 + kq];
      #pragma unroll
      for (int ni=0;ni<4;ni++) bf[ni] = *(const half8*)&Bs1[(wn*64 + ni*16 + ar)*32 + kq];
      #pragma unroll
      for (int mi=0;mi<4;mi++)
        #pragma unroll
        for (int ni=0;ni<4;ni++)
          acc[mi][ni] = __builtin_amdgcn_mfma_f32_16x16x32_f16(af[mi], bf[ni], acc[mi][ni], 0, 0, 0);
    }
    __syncthreads();
  }
  int rb = (lane >> 4) * 4, cb = lane & 15;
  #pragma unroll
  for (int ni=0;ni<4;ni++){
    int cn = n0 + wn*64 + ni*16 + cb;
    float bz = bias[cn];
    #pragma unroll
    for (int mi=0;mi<4;mi++){
      int rm = m0 + wm*64 + mi*16 + rb;
      #pragma unroll
      for (int r=0;r<4;r++){
        float v = acc[mi][ni][r] + bz;
        if (ACT==1) v = 0.5f*v*(1.0f+erff(v*0.70710678118f));
        if (OUT16) Ch[(size_t)(rm+r)*ldc + cn] = (f16)v;
        else       Cf[(size_t)(rm+r)*ldc + cn] = v;
      }
    }
  }
}

// ---------------- beta/g projections ----------------
__global__ __launch_bounds__(256) void betag_kernel(
    const float* __restrict__ x, const float* __restrict__ Wb, const float* __restrict__ bb,
    const float* __restrict__ Wg, const float* __restrict__ bg,
    const int* __restrict__ mask, float* __restrict__ beta, float* __restrict__ g)
{
  __shared__ float Ws[384*25];
  for (int idx = threadIdx.x; idx < 384*12; idx += 256){
    int k = idx/12, j = idx - k*12;
    Ws[k*25+j]    = Wb[idx];
    Ws[k*25+12+j] = Wg[idx];
  }
  __syncthreads();
  int wv = threadIdx.x>>6, lane = threadIdx.x&63;
  int row = blockIdx.x*4 + wv;
  const float* xr = x + (size_t)row*DD;
  float accb[12], accg[12];
  #pragma unroll
  for (int j=0;j<12;j++){ accb[j]=0.f; accg[j]=0.f; }
  #pragma unroll
  for (int i=0;i<6;i++){
    int k = lane + 64*i;
    float xv = xr[k];
    const float* wr = &Ws[k*25];
    #pragma unroll
    for (int j=0;j<12;j++){ accb[j] += xv*wr[j]; accg[j] += xv*wr[12+j]; }
  }
  #pragma unroll
  for (int j=0;j<12;j++){
    #pragma unroll
    for (int off=32; off>=1; off>>=1){
      accb[j]+=__shfl_xor(accb[j],off);
      accg[j]+=__shfl_xor(accg[j],off);
    }
  }
  if (lane==0){
    float mk = (float)mask[row];
    #pragma unroll
    for (int j=0;j<12;j++){
      beta[(size_t)row*HH + j] = sigmoidf_(accb[j]+bb[j]) * mk;
      g[(size_t)row*HH + j]    = sigmoidf_(accg[j]+bg[j]);
    }
  }
}

// ---------------- DeltaNet dual-state scan (R6 config: f32 LDS + packed f32x2 math) ----------------
// REVERTED to best-measured config (153 us). R10 (4-wave split: 185) and R11 (k-half
// split: 160) both regressed despite halved LDS reads -> per-step cost is NOT explained
// by ds_read count, chain shuffles, or barrier count at source level. Leave as-is.
// One wave (=block) per (b,h). Lanes 0-31 fast, 32-63 slow; lane owns col=lane&31.
__global__ __launch_bounds__(64) void scan_kernel(
  f16* qkv,
  const float* __restrict__ bp, const float* __restrict__ gp,
  const float* __restrict__ flp, const float* __restrict__ slp)
{
  __shared__ float Kf[2][TB][32];
  __shared__ float Qf[2][TB][32];
  __shared__ float Vf[2][TB][32];
  __shared__ float Bg[2][2][TB];
  __shared__ float Of[TB][64];
  int blk = blockIdx.x;
  int b = blk / HH, h = blk - b*HH;
  int lane = threadIdx.x;
  int col = lane & 31;
  float a = sigmoidf_((lane < 32) ? flp[h] : slp[h]);
  f32x2 a2 = {a, a};
  f32x2 S2[16];
  #pragma unroll
  for (int j=0;j<16;j++) S2[j] = (f32x2){0.f,0.f};
  size_t base = ((size_t)b*SS)*LDX + (size_t)h*DKK;
  f16* qb = qkv + base;
  const f16* kb = qkv + base + 384;
  const f16* vb = qkv + base + 768;
  const float* bbp = bp + ((size_t)b*SS)*HH + h;
  const float* gbp = gp + ((size_t)b*SS)*HH + h;

  int st0 = lane >> 2, part = lane & 3;
  uint4 kv[2], qv[2], vv[2]; float bgv;

  #define LOADG(T0) do {                                                       \
    _Pragma("unroll")                                                          \
    for (int r=0;r<2;r++){                                                     \
      int st = (T0) + r*16 + st0;                                              \
      size_t off = (size_t)st*LDX + part*8;                                    \
      kv[r] = *(const uint4*)(kb + off);                                       \
      qv[r] = *(const uint4*)(qb + off);                                       \
      vv[r] = *(const uint4*)(vb + off);                                       \
    }                                                                          \
    int tb_ = (T0) + (lane & 31);                                              \
    bgv = (lane < 32) ? bbp[(size_t)tb_*HH] : gbp[(size_t)tb_*HH];             \
  } while(0)

  #define STAGE(BUF) do {                                                      \
    _Pragma("unroll")                                                          \
    for (int r=0;r<2;r++){                                                     \
      int s = r*16 + st0;                                                      \
      float kf[8], qf[8], vf[8];                                               \
      kf[0]=h2f_lo(kv[r].x); kf[1]=h2f_hi(kv[r].x); kf[2]=h2f_lo(kv[r].y);     \
      kf[3]=h2f_hi(kv[r].y); kf[4]=h2f_lo(kv[r].z); kf[5]=h2f_hi(kv[r].z);     \
      kf[6]=h2f_lo(kv[r].w); kf[7]=h2f_hi(kv[r].w);                            \
      qf[0]=h2f_lo(qv[r].x); qf[1]=h2f_hi(qv[r].x); qf[2]=h2f_lo(qv[r].y);     \
      qf[3]=h2f_hi(qv[r].y); qf[4]=h2f_lo(qv[r].z); qf[5]=h2f_hi(qv[r].z);     \
      qf[6]=h2f_lo(qv[r].w); qf[7]=h2f_hi(qv[r].w);                            \
      vf[0]=h2f_lo(vv[r].x); vf[1]=h2f_hi(vv[r].x); vf[2]=h2f_lo(vv[r].y);     \
      vf[3]=h2f_hi(vv[r].y); vf[4]=h2f_lo(vv[r].z); vf[5]=h2f_hi(vv[r].z);     \
      vf[6]=h2f_lo(vv[r].w); vf[7]=h2f_hi(vv[r].w);                            \
      float ss = 0.f;                                                          \
      _Pragma("unroll")                                                        \
      for (int i=0;i<8;i++) ss += kf[i]*kf[i];                                 \
      ss += __shfl_xor(ss, 1); ss += __shfl_xor(ss, 2);                        \
      float sc = 1.0f/(sqrtf(ss)+1e-6f);                                       \
      float4 t;                                                                \
      t.x=kf[0]*sc; t.y=kf[1]*sc; t.z=kf[2]*sc; t.w=kf[3]*sc;                  \
      *(float4*)&Kf[BUF][s][part*8] = t;                                       \
      t.x=kf[4]*sc; t.y=kf[5]*sc; t.z=kf[6]*sc; t.w=kf[7]*sc;                  \
      *(float4*)&Kf[BUF][s][part*8+4] = t;                                     \
      t.x=qf[0]; t.y=qf[1]; t.z=qf[2]; t.w=qf[3];                              \
      *(float4*)&Qf[BUF][s][part*8] = t;                                       \
      t.x=qf[4]; t.y=qf[5]; t.z=qf[6]; t.w=qf[7];                              \
      *(float4*)&Qf[BUF][s][part*8+4] = t;                                     \
      t.x=vf[0]; t.y=vf[1]; t.z=vf[2]; t.w=vf[3];                              \
      *(float4*)&Vf[BUF][s][part*8] = t;                                       \
      t.x=vf[4]; t.y=vf[5]; t.z=vf[6]; t.w=vf[7];                              \
      *(float4*)&Vf[BUF][s][part*8+4] = t;                                     \
    }                                                                          \
    Bg[BUF][lane>>5][lane&31] = bgv;                                           \
  } while(0)

  #define LDSTEP(BUF,S,KR,QR,VT,BT) do {                                       \
    const float4* k4_ = (const float4*)&Kf[BUF][S][0];                         \
    const float4* q4_ = (const float4*)&Qf[BUF][S][0];                         \
    _Pragma("unroll")                                                          \
    for (int j=0;j<8;j++){ KR[j]=k4_[j]; QR[j]=q4_[j]; }                       \
    VT = Vf[BUF][S][col]; BT = Bg[BUF][0][S];                                  \
  } while(0)

  #define STEP(KR,QR,VT,BT,S) do {                                            \
    const f32x2* k2_ = (const f32x2*)KR;                                       \
    const f32x2* q2_ = (const f32x2*)QR;                                       \
    f32x2 rA={0.f,0.f},rB={0.f,0.f},rC={0.f,0.f},rD={0.f,0.f};                 \
    _Pragma("unroll")                                                          \
    for (int j=0;j<16;j+=4){                                                   \
      rA += S2[j+0]*k2_[j+0]; rB += S2[j+1]*k2_[j+1];                          \
      rC += S2[j+2]*k2_[j+2]; rD += S2[j+3]*k2_[j+3]; }                        \
    f32x2 rr = (rA+rB)+(rC+rD);                                                \
    float rf = rr.x + rr.y;                                                    \
    float c_ = (BT)*((VT) - rf);                                               \
    f32x2 c2 = {c_, c_};                                                       \
    _Pragma("unroll")                                                          \
    for (int j=0;j<16;j++) S2[j] = a2*S2[j] + c2*k2_[j];                       \
    f32x2 oA={0.f,0.f},oB={0.f,0.f},oC={0.f,0.f},oD={0.f,0.f};                 \
    _Pragma("unroll")                                                          \
    for (int j=0;j<16;j+=4){                                                   \
      oA += S2[j+0]*q2_[j+0]; oB += S2[j+1]*q2_[j+1];                          \
      oC += S2[j+2]*q2_[j+2]; oD += S2[j+3]*q2_[j+3]; }                        \
    f32x2 oo = (oA+oB)+(oC+oD);                                                \
    Of[S][lane] = oo.x + oo.y;                                                 \
  } while(0)

  #define COMBINE(BUF,T0) do {                                                 \
    _Pragma("unroll")                                                          \
    for (int i=0;i<16;i++){                                                    \
      int idx = i*64 + lane;                                                   \
      int s_ = idx >> 5, c_ = idx & 31;                                        \
      float fv = Of[s_][c_];                                                   \
      float sv = Of[s_][c_+32];                                                \
      float gv = Bg[BUF][1][s_];                                               \
      qb[(size_t)((T0)+s_)*LDX + c_] = (f16)(gv*fv + (1.0f-gv)*sv);            \
    }                                                                          \
  } while(0)

  LOADG(0);
  STAGE(0);
  __syncthreads();

  float4 kA[8], qA[8], kB[8], qB[8];
  float vA, bA, vB, bB;

  for (int tile=0; tile<SS/TB; tile++){
    int buf = tile & 1;
    if (tile < SS/TB-1) LOADG((tile+1)*TB);
    LDSTEP(buf, 0, kA, qA, vA, bA);
    #pragma unroll
    for (int s=0; s<TB; s+=2){
      if (s+1 < TB) LDSTEP(buf, s+1, kB, qB, vB, bB);
      STEP(kA, qA, vA, bA, s);
      if (s+2 < TB) LDSTEP(buf, s+2, kA, qA, vA, bA);
      STEP(kB, qB, vB, bB, s+1);
    }
    if (tile < SS/TB-1) STAGE(1-buf);
    COMBINE(buf, tile*TB);
    __syncthreads();
  }
  #undef LOADG
  #undef STAGE
  #undef LDSTEP
  #undef STEP
  #undef COMBINE
}

// ---------------- masked mean-pool + L2 normalize ----------------
__global__ __launch_bounds__(384) void pool_kernel(
    const float* __restrict__ x, const int* __restrict__ mask, float* __restrict__ out)
{
  __shared__ float red[384];
  __shared__ float tot;
  int b = blockIdx.x, d = threadIdx.x;
  const float* xb = x + (size_t)b*SS*DD;
  const int* mb = mask + b*SS;
  float s=0.f, sm=0.f;
  for (int t=0;t<SS;t++){ float m=(float)mb[t]; s += xb[(size_t)t*DD+d]*m; sm += m; }
  float emb = s / fmaxf(sm, 1e-9f);
  red[d] = emb*emb;
  __syncthreads();
  for (int off=192; off>=3; off>>=1){
    if (d < off) red[d] += red[d+off];
    __syncthreads();
  }
  if (d==0) tot = red[0]+red[1]+red[2];
  __syncthreads();
  out[(size_t)b*DD + d] = emb * rsqrtf(tot);
}

extern "C" void kernel_launch(void* const* d_in, const int* in_sizes, int n_in,
                              void* d_out, int out_size, void* d_ws, size_t ws_size,
                              hipStream_t stream)
{
  const int*   ids  = (const int*)d_in[0];
  const int*   amask= (const int*)d_in[1];
  const float* we   = (const float*)d_in[2];
  const float* pe   = (const float*)d_in[3];
  const float* te   = (const float*)d_in[4];
  const float* elnw = (const float*)d_in[5];
  const float* elnb = (const float*)d_in[6];
  const float* Wq   = (const float*)d_in[7];
  const float* bq   = (const float*)d_in[8];
  const float* Wk   = (const float*)d_in[9];
  const float* bk   = (const float*)d_in[10];
  const float* Wv   = (const float*)d_in[11];
  const float* bv   = (const float*)d_in[12];
  const float* Wb   = (const float*)d_in[13];
  const float* bb   = (const float*)d_in[14];
  const float* Wg   = (const float*)d_in[15];
  const float* bgp  = (const float*)d_in[16];
  const float* Wo   = (const float*)d_in[17];
  const float* bo   = (const float*)d_in[18];
  const float* fl   = (const float*)d_in[19];
  const float* sl   = (const float*)d_in[20];
  const float* alnw = (const float*)d_in[21];
  const float* alnb = (const float*)d_in[22];
  const float* W1   = (const float*)d_in[23];
  const float* b1   = (const float*)d_in[24];
  const float* W2   = (const float*)d_in[25];
  const float* b2   = (const float*)d_in[26];
  const float* flnw = (const float*)d_in[27];
  const float* flnb = (const float*)d_in[28];
  float* out = (float*)d_out;
  float* w = (float*)d_ws;

  // workspace (float slots), total 49,355,520 f = 197.4 MB
  // x    [0, 12.58M f)           : residual f32
  // xh   [12.58M, 18.87M f)      : x as f16; FFN2 f16 output reuses this buffer
  // qkvh [18.87M, 37.75M f)      : qkv rows [32768][1152] f16
  // f2   [37.75M, 44.04M f)      : tail of full-M hidden; beta/gbuf live here
  //                                (attention phase only — temporally disjoint)
  // hidden full-M = qkvh+f2 = 50,331,648 h == 32768*1536 exactly
  // wt   [44.04M, 49.35M f)      : transposed f16 weights (6 layers)
  float* x    = w;                      // 12,582,912 f
  f16*  xh   = (f16*)(w + 12582912);    // 12,582,912 h
  f16*  qkvh = (f16*)(w + 18874368);    // 37,748,736 h  [row][1152]
  float* f2   = w + 37748736;           //  6,291,456 f region
  float* beta = f2 + 3145728;           //    393,216 f
  float* gbuf = beta + 393216;          //    393,216 f
  f16*  wt   = (f16*)(w + 44040192);    // 10,616,832 h (all 6 layers)
  float* bqkv = w + 49348608;           //      6,912 f
  f16*  hb   = qkvh;                    // full-M FFN hidden [32768][1536] h (overlays qkvh+f2)

  embed_ln_kernel<<<MROWS/4, 256, 0, stream>>>(ids, we, pe, te, elnw, elnb, x, xh);
  biaspack_kernel<<<27,256,0,stream>>>(bq, bk, bv, bqkv);
  wtrans_kernel<<<LL*1728,256,0,stream>>>(Wq, Wk, Wv, Wo, W1, W2, wt);

  for (int l=0;l<LL;l++){
    f16* wl = wt + (size_t)l*1769472;

    // fused QKV: [32768 x 1152] = xh @ [Wq|Wk|Wv]^T
    gemm_f16<0,1><<<dim3(9,256),256,0,stream>>>(xh, wl, bqkv + l*LDX, nullptr, qkvh,
                                                MROWS, LDX, DD, DD, LDX);

    betag_kernel<<<MROWS/4,256,0,stream>>>(x, Wb + (size_t)l*DD*HH, bb + l*HH,
                                           Wg + (size_t)l*DD*HH, bgp + l*HH,
                                           amask, beta, gbuf);
    scan_kernel<<<BB*HH,64,0,stream>>>(qkvh, beta, gbuf, fl + l*HH, sl + l*HH);

    // o-proj full-M: A = attn-out = qkv[:,0:384] (lda=1152), C(f16) -> dead k-slot qkv[:,384:768]
    gemm_f16<0,1><<<dim3(3,256),256,0,stream>>>(qkvh, wl+442368, bo+l*DD, nullptr,
                                                qkvh + 384, MROWS, DD, DD, LDX, LDX);
    add_ln_kernel<1><<<MROWS/4,256,0,stream>>>(x, xh, qkvh + 384, alnw+l*DD, alnb+l*DD, 0, LDX);

    // FFN full-M (hidden overlays qkvh+f2 exactly; qkv dead after add_ln above).
    // FFN1: grid (12,256) = 3072 blocks = 12/CU. FFN2: grid (3,256) = 768 = 3/CU
    // (was 1.5/CU when M-chunked -> latency-bound at K=1536). FFN2 f16 out -> xh buffer
    // (dead between FFN1's last read and add_ln's rewrite; add_ln reads y before writing xh).
    gemm_f16<1,1><<<dim3(12,256),256,0,stream>>>(xh, wl+589824, b1+l*FFF, nullptr, hb,
                                                 MROWS, FFF, DD, DD, FFF);
    gemm_f16<0,1><<<dim3(3,256),256,0,stream>>>(hb, wl+1179648, b2+l*DD, nullptr, xh,
                                                MROWS, DD, FFF, FFF, DD);
    add_ln_kernel<1><<<MROWS/4,256,0,stream>>>(x, xh, xh, flnw+l*DD, flnb+l*DD, 0, DD);
  }

  pool_kernel<<<BB,384,0,stream>>>(x, amask, out);
}

// Round 4
// 3373.456 us; speedup vs baseline: 1.0660x; 1.0386x over previous
//
#include <hip/hip_runtime.h>
#include <math.h>

#define DD 384
#define HH 12
#define DKK 32
#define LL 6
#define FFF 1536
#define BB 64
#define SS 512
#define MROWS (BB*SS)   // 32768
#define TB 32           // scan time-tile
#define LDX 1152        // qkv row stride

typedef _Float16 f16;
typedef _Float16 half8 __attribute__((ext_vector_type(8)));
typedef _Float16 h2 __attribute__((ext_vector_type(2)));
typedef float f32x4 __attribute__((ext_vector_type(4)));
typedef float f32x2 __attribute__((ext_vector_type(2)));

__device__ __forceinline__ float sigmoidf_(float x){ return 1.0f/(1.0f+expf(-x)); }

__device__ __forceinline__ float h2f_lo(unsigned int u){
  union { unsigned short s; f16 h; } c; c.s = (unsigned short)(u & 0xffffu); return (float)c.h;
}
__device__ __forceinline__ float h2f_hi(unsigned int u){
  union { unsigned short s; f16 h; } c; c.s = (unsigned short)(u >> 16); return (float)c.h;
}

__device__ __forceinline__ void gl2lds16(const void* g, void* l){
  __builtin_amdgcn_global_load_lds((const __attribute__((address_space(1))) void*)g,
                                   (__attribute__((address_space(3))) void*)l, 16, 0, 0);
}

// ---------------- embedding + LN (writes fp32 x and f16 xh) ----------------
__global__ __launch_bounds__(256) void embed_ln_kernel(
    const int* __restrict__ ids, const float* __restrict__ we,
    const float* __restrict__ pe, const float* __restrict__ te,
    const float* __restrict__ w, const float* __restrict__ b,
    float* __restrict__ x, f16* __restrict__ xh)
{
  int wv = threadIdx.x >> 6, lane = threadIdx.x & 63;
  int row = blockIdx.x * 4 + wv;
  int s = row & (SS-1);
  int id = ids[row];
  const float* wep = we + (size_t)id * DD;
  const float* pep = pe + (size_t)s * DD;
  float vals[6]; float sum = 0.f;
  #pragma unroll
  for (int i=0;i<6;i++){ int d = lane + 64*i; vals[i] = wep[d] + pep[d] + te[d]; sum += vals[i]; }
  #pragma unroll
  for (int off=32; off>=1; off>>=1) sum += __shfl_xor(sum, off);
  float mean = sum * (1.0f/DD);
  float vs = 0.f;
  #pragma unroll
  for (int i=0;i<6;i++){ float dv = vals[i]-mean; vs += dv*dv; }
  #pragma unroll
  for (int off=32; off>=1; off>>=1) vs += __shfl_xor(vs, off);
  float inv = rsqrtf(vs*(1.0f/DD) + 1e-12f);
  float* xr = x + (size_t)row*DD;
  f16* xhr = xh + (size_t)row*DD;
  #pragma unroll
  for (int i=0;i<6;i++){ int d = lane + 64*i; float o = (vals[i]-mean)*inv*w[d] + b[d]; xr[d]=o; xhr[d]=(f16)o; }
}

// ---------------- x = LN(x + y); y f32 (YH=0) or f16 (YH=1), stride ldy ----------------
template<int YH>
__global__ __launch_bounds__(256) void add_ln_kernel(
    float* __restrict__ x, f16* __restrict__ xh, const void* __restrict__ yp,
    const float* __restrict__ w, const float* __restrict__ b, int row0, int ldy)
{
  int wv = threadIdx.x >> 6, lane = threadIdx.x & 63;
  int rrel = blockIdx.x * 4 + wv;
  int row = row0 + rrel;
  float* xr = x + (size_t)row*DD;
  f16* xhr = xh + (size_t)row*DD;
  float vals[6]; float sum = 0.f;
  #pragma unroll
  for (int i=0;i<6;i++){
    int d = lane + 64*i;
    float yv;
    if (YH) yv = (float)((const f16*)yp)[(size_t)rrel*ldy + d];
    else    yv = ((const float*)yp)[(size_t)rrel*ldy + d];
    vals[i] = xr[d] + yv; sum += vals[i];
  }
  #pragma unroll
  for (int off=32; off>=1; off>>=1) sum += __shfl_xor(sum, off);
  float mean = sum * (1.0f/DD);
  float vs = 0.f;
  #pragma unroll
  for (int i=0;i<6;i++){ float dv = vals[i]-mean; vs += dv*dv; }
  #pragma unroll
  for (int off=32; off>=1; off>>=1) vs += __shfl_xor(vs, off);
  float inv = rsqrtf(vs*(1.0f/DD) + 1e-12f);
  #pragma unroll
  for (int i=0;i<6;i++){ int d = lane + 64*i; float o = (vals[i]-mean)*inv*w[d] + b[d]; xr[d]=o; xhr[d]=(f16)o; }
}

// ---------------- bias pack: [bq;bk;bv] per layer -> 1152 each ----------------
__global__ __launch_bounds__(256) void biaspack_kernel(
    const float* __restrict__ bq, const float* __restrict__ bk, const float* __restrict__ bv,
    float* __restrict__ dst)
{
  int i = blockIdx.x*256 + threadIdx.x;   // 6912 total
  if (i >= LL*LDX) return;
  int l = i / LDX, r = i - l*LDX;
  float v;
  if (r < 384) v = bq[l*DD + r];
  else if (r < 768) v = bk[l*DD + r-384];
  else v = bv[l*DD + r-768];
  dst[i] = v;
}

// ---------------- weight transpose + f32->f16, ALL layers in one dispatch ----------------
__global__ __launch_bounds__(256) void wtrans_kernel(
  const float* __restrict__ Wq, const float* __restrict__ Wk, const float* __restrict__ Wv,
  const float* __restrict__ Wo, const float* __restrict__ W1, const float* __restrict__ W2,
  f16* __restrict__ Wt)
{
  __shared__ float T[32][33];
  int l = blockIdx.x / 1728, bidx = blockIdx.x % 1728;
  const float* src; f16* dst; int K, N, tile;
  if (bidx < 576){ int m = bidx/144; tile = bidx - m*144; K=384; N=384;
    const float* w4[4] = {Wq + (size_t)l*147456, Wk + (size_t)l*147456,
                          Wv + (size_t)l*147456, Wo + (size_t)l*147456};
    src = w4[m]; dst = Wt + (size_t)l*1769472 + m*147456; }
  else if (bidx < 1152){ tile = bidx-576; K=384; N=1536;
    src = W1 + (size_t)l*589824; dst = Wt + (size_t)l*1769472 + 589824; }
  else { tile = bidx-1152; K=1536; N=384;
    src = W2 + (size_t)l*589824; dst = Wt + (size_t)l*1769472 + 1179648; }
  int tN = N>>5;
  int tk = tile / tN, tn = tile - tk*tN;
  int k0 = tk<<5, n0 = tn<<5;
  int r = threadIdx.x >> 3, c4 = (threadIdx.x & 7) << 2;
  float4 vv = *(const float4*)(src + (size_t)(k0+r)*N + n0 + c4);
  T[r][c4+0]=vv.x; T[r][c4+1]=vv.y; T[r][c4+2]=vv.z; T[r][c4+3]=vv.w;
  __syncthreads();
  f16* dp = dst + (size_t)(n0+r)*K + k0 + c4;
  #pragma unroll
  for (int j=0;j<4;j++) dp[j] = (f16)T[c4+j][r];
}

// ---------------- f16 MFMA GEMM, BK=64, double-buffered 2-phase ----------------
// R13: was stage -> sync -> compute -> sync (2 barriers/K-step, stage fully exposed;
// below T3's "minimum 2-phase"). Now: double-buffered LDS (64 KB, 2 blocks/CU kept),
// prefetch next K-tile BEFORE computing current, ONE barrier per K-step (its implicit
// vmcnt(0) drain lands after ~32 MFMA + 16 ds_read of overlap). + bijective chunked
// XCD swizzle (T1): each XCD takes a contiguous n-column range -> B-panels L2-resident.
// All grids here have nwg % 8 == 0 and M,N divisible by 128 (no partial tiles).
template<int ACT, int OUT16>
__global__ __launch_bounds__(256) void gemm_f16(
    const f16* __restrict__ A, const f16* __restrict__ BT,
    const float* __restrict__ bias, float* __restrict__ Cf, f16* __restrict__ Ch,
    int M, int N, int K, int lda, int ldc)
{
  __shared__ __align__(16) f16 As[2][2][128*32];
  __shared__ __align__(16) f16 Bs[2][2][128*32];
  int tid = threadIdx.x, lane = tid & 63, wave = tid >> 6;
  int wm = wave >> 1, wn = wave & 1;
  // chunked XCD swizzle: flat bid -> (xcd, idx) -> x-major tile enumeration
  int gx = gridDim.x, gy = gridDim.y;
  int bid = blockIdx.y * gx + blockIdx.x;
  int chunk = (gx * gy) >> 3;
  int nf = (bid & 7) * chunk + (bid >> 3);
  int tx = nf / gy, ty = nf - tx * gy;
  int n0 = tx * 128, m0 = ty * 128;
  f32x4 acc[4][4] = {};
  int seg0 = wave*2048 + lane*16;
  int ar = lane & 15, kq = (lane >> 4) * 8;

  #define GSTAGE(PB, K0) do {                                                  \
    _Pragma("unroll")                                                          \
    for (int i=0;i<2;i++){                                                     \
      int seg = seg0 + i*1024;                                                 \
      int e = seg >> 1; int row = e >> 5; int kk = e & 31;                     \
      const f16* ap = A  + (size_t)(m0+row)*lda + (K0) + kk;                   \
      const f16* bp = BT + (size_t)(n0+row)*K   + (K0) + kk;                   \
      gl2lds16(ap,      (char*)As[PB][0] + seg);                               \
      gl2lds16(ap + 32, (char*)As[PB][1] + seg);                               \
      gl2lds16(bp,      (char*)Bs[PB][0] + seg);                               \
      gl2lds16(bp + 32, (char*)Bs[PB][1] + seg);                               \
    }                                                                          \
  } while(0)

  GSTAGE(0, 0);
  __syncthreads();
  int nk = K >> 6;
  int pb = 0;
  for (int t=0; t<nk; t++){
    if (t+1 < nk) GSTAGE(pb^1, (t+1)*64);
    #pragma unroll
    for (int h=0; h<2; h++){
      half8 af[4], bfr[4];
      #pragma unroll
      for (int mi=0;mi<4;mi++) af[mi]  = *(const half8*)&As[pb][h][(wm*64 + mi*16 + ar)*32 + kq];
      #pragma unroll
      for (int ni=0;ni<4;ni++) bfr[ni] = *(const half8*)&Bs[pb][h][(wn*64 + ni*16 + ar)*32 + kq];
      #pragma unroll
      for (int mi=0;mi<4;mi++)
        #pragma unroll
        for (int ni=0;ni<4;ni++)
          acc[mi][ni] = __builtin_amdgcn_mfma_f32_16x16x32_f16(af[mi], bfr[ni], acc[mi][ni], 0, 0, 0);
    }
    __syncthreads();   // drains prefetch vmcnt + guards buffer swap (one barrier/K-step)
    pb ^= 1;
  }
  #undef GSTAGE

  int rb = (lane >> 4) * 4, cb = lane & 15;
  #pragma unroll
  for (int ni=0;ni<4;ni++){
    int cn = n0 + wn*64 + ni*16 + cb;
    float bz = bias[cn];
    #pragma unroll
    for (int mi=0;mi<4;mi++){
      int rm = m0 + wm*64 + mi*16 + rb;
      #pragma unroll
      for (int r=0;r<4;r++){
        float v = acc[mi][ni][r] + bz;
        if (ACT==1) v = 0.5f*v*(1.0f+erff(v*0.70710678118f));
        if (OUT16) Ch[(size_t)(rm+r)*ldc + cn] = (f16)v;
        else       Cf[(size_t)(rm+r)*ldc + cn] = v;
      }
    }
  }
}

// ---------------- beta/g projections ----------------
__global__ __launch_bounds__(256) void betag_kernel(
    const float* __restrict__ x, const float* __restrict__ Wb, const float* __restrict__ bb,
    const float* __restrict__ Wg, const float* __restrict__ bg,
    const int* __restrict__ mask, float* __restrict__ beta, float* __restrict__ g)
{
  __shared__ float Ws[384*25];
  for (int idx = threadIdx.x; idx < 384*12; idx += 256){
    int k = idx/12, j = idx - k*12;
    Ws[k*25+j]    = Wb[idx];
    Ws[k*25+12+j] = Wg[idx];
  }
  __syncthreads();
  int wv = threadIdx.x>>6, lane = threadIdx.x&63;
  int row = blockIdx.x*4 + wv;
  const float* xr = x + (size_t)row*DD;
  float accb[12], accg[12];
  #pragma unroll
  for (int j=0;j<12;j++){ accb[j]=0.f; accg[j]=0.f; }
  #pragma unroll
  for (int i=0;i<6;i++){
    int k = lane + 64*i;
    float xv = xr[k];
    const float* wr = &Ws[k*25];
    #pragma unroll
    for (int j=0;j<12;j++){ accb[j] += xv*wr[j]; accg[j] += xv*wr[12+j]; }
  }
  #pragma unroll
  for (int j=0;j<12;j++){
    #pragma unroll
    for (int off=32; off>=1; off>>=1){
      accb[j]+=__shfl_xor(accb[j],off);
      accg[j]+=__shfl_xor(accg[j],off);
    }
  }
  if (lane==0){
    float mk = (float)mask[row];
    #pragma unroll
    for (int j=0;j<12;j++){
      beta[(size_t)row*HH + j] = sigmoidf_(accb[j]+bb[j]) * mk;
      g[(size_t)row*HH + j]    = sigmoidf_(accg[j]+bg[j]);
    }
  }
}

// ---------------- DeltaNet dual-state scan (R6 config: f32 LDS + packed f32x2 math) ----------------
// R6 config retained. Measured 153 us (R0 session) / 198 us (R3 session) with IDENTICAL
// source + launch -> +-25% session-level clock/power variance on this latency-bound kernel.
// R10 (4-wave) and R11 (k-half) restructures both regressed. Do not touch.
__global__ __launch_bounds__(64) void scan_kernel(
  f16* qkv,
  const float* __restrict__ bp, const float* __restrict__ gp,
  const float* __restrict__ flp, const float* __restrict__ slp)
{
  __shared__ float Kf[2][TB][32];
  __shared__ float Qf[2][TB][32];
  __shared__ float Vf[2][TB][32];
  __shared__ float Bg[2][2][TB];
  __shared__ float Of[TB][64];
  int blk = blockIdx.x;
  int b = blk / HH, h = blk - b*HH;
  int lane = threadIdx.x;
  int col = lane & 31;
  float a = sigmoidf_((lane < 32) ? flp[h] : slp[h]);
  f32x2 a2 = {a, a};
  f32x2 S2[16];
  #pragma unroll
  for (int j=0;j<16;j++) S2[j] = (f32x2){0.f,0.f};
  size_t base = ((size_t)b*SS)*LDX + (size_t)h*DKK;
  f16* qb = qkv + base;
  const f16* kb = qkv + base + 384;
  const f16* vb = qkv + base + 768;
  const float* bbp = bp + ((size_t)b*SS)*HH + h;
  const float* gbp = gp + ((size_t)b*SS)*HH + h;

  int st0 = lane >> 2, part = lane & 3;
  uint4 kv[2], qv[2], vv[2]; float bgv;

  #define LOADG(T0) do {                                                       \
    _Pragma("unroll")                                                          \
    for (int r=0;r<2;r++){                                                     \
      int st = (T0) + r*16 + st0;                                              \
      size_t off = (size_t)st*LDX + part*8;                                    \
      kv[r] = *(const uint4*)(kb + off);                                       \
      qv[r] = *(const uint4*)(qb + off);                                       \
      vv[r] = *(const uint4*)(vb + off);                                       \
    }                                                                          \
    int tb_ = (T0) + (lane & 31);                                              \
    bgv = (lane < 32) ? bbp[(size_t)tb_*HH] : gbp[(size_t)tb_*HH];             \
  } while(0)

  #define STAGE(BUF) do {                                                      \
    _Pragma("unroll")                                                          \
    for (int r=0;r<2;r++){                                                     \
      int s = r*16 + st0;                                                      \
      float kf[8], qf[8], vf[8];                                               \
      kf[0]=h2f_lo(kv[r].x); kf[1]=h2f_hi(kv[r].x); kf[2]=h2f_lo(kv[r].y);     \
      kf[3]=h2f_hi(kv[r].y); kf[4]=h2f_lo(kv[r].z); kf[5]=h2f_hi(kv[r].z);     \
      kf[6]=h2f_lo(kv[r].w); kf[7]=h2f_hi(kv[r].w);                            \
      qf[0]=h2f_lo(qv[r].x); qf[1]=h2f_hi(qv[r].x); qf[2]=h2f_lo(qv[r].y);     \
      qf[3]=h2f_hi(qv[r].y); qf[4]=h2f_lo(qv[r].z); qf[5]=h2f_hi(qv[r].z);     \
      qf[6]=h2f_lo(qv[r].w); qf[7]=h2f_hi(qv[r].w);                            \
      vf[0]=h2f_lo(vv[r].x); vf[1]=h2f_hi(vv[r].x); vf[2]=h2f_lo(vv[r].y);     \
      vf[3]=h2f_hi(vv[r].y); vf[4]=h2f_lo(vv[r].z); vf[5]=h2f_hi(vv[r].z);     \
      vf[6]=h2f_lo(vv[r].w); vf[7]=h2f_hi(vv[r].w);                            \
      float ss = 0.f;                                                          \
      _Pragma("unroll")                                                        \
      for (int i=0;i<8;i++) ss += kf[i]*kf[i];                                 \
      ss += __shfl_xor(ss, 1); ss += __shfl_xor(ss, 2);                        \
      float sc = 1.0f/(sqrtf(ss)+1e-6f);                                       \
      float4 t;                                                                \
      t.x=kf[0]*sc; t.y=kf[1]*sc; t.z=kf[2]*sc; t.w=kf[3]*sc;                  \
      *(float4*)&Kf[BUF][s][part*8] = t;                                       \
      t.x=kf[4]*sc; t.y=kf[5]*sc; t.z=kf[6]*sc; t.w=kf[7]*sc;                  \
      *(float4*)&Kf[BUF][s][part*8+4] = t;                                     \
      t.x=qf[0]; t.y=qf[1]; t.z=qf[2]; t.w=qf[3];                              \
      *(float4*)&Qf[BUF][s][part*8] = t;                                       \
      t.x=qf[4]; t.y=qf[5]; t.z=qf[6]; t.w=qf[7];                              \
      *(float4*)&Qf[BUF][s][part*8+4] = t;                                     \
      t.x=vf[0]; t.y=vf[1]; t.z=vf[2]; t.w=vf[3];                              \
      *(float4*)&Vf[BUF][s][part*8] = t;                                       \
      t.x=vf[4]; t.y=vf[5]; t.z=vf[6]; t.w=vf[7];                              \
      *(float4*)&Vf[BUF][s][part*8+4] = t;                                     \
    }                                                                          \
    Bg[BUF][lane>>5][lane&31] = bgv;                                           \
  } while(0)

  #define LDSTEP(BUF,S,KR,QR,VT,BT) do {                                       \
    const float4* k4_ = (const float4*)&Kf[BUF][S][0];                         \
    const float4* q4_ = (const float4*)&Qf[BUF][S][0];                         \
    _Pragma("unroll")                                                          \
    for (int j=0;j<8;j++){ KR[j]=k4_[j]; QR[j]=q4_[j]; }                       \
    VT = Vf[BUF][S][col]; BT = Bg[BUF][0][S];                                  \
  } while(0)

  #define STEP(KR,QR,VT,BT,S) do {                                            \
    const f32x2* k2_ = (const f32x2*)KR;                                       \
    const f32x2* q2_ = (const f32x2*)QR;                                       \
    f32x2 rA={0.f,0.f},rB={0.f,0.f},rC={0.f,0.f},rD={0.f,0.f};                 \
    _Pragma("unroll")                                                          \
    for (int j=0;j<16;j+=4){                                                   \
      rA += S2[j+0]*k2_[j+0]; rB += S2[j+1]*k2_[j+1];                          \
      rC += S2[j+2]*k2_[j+2]; rD += S2[j+3]*k2_[j+3]; }                        \
    f32x2 rr = (rA+rB)+(rC+rD);                                                \
    float rf = rr.x + rr.y;                                                    \
    float c_ = (BT)*((VT) - rf);                                               \
    f32x2 c2 = {c_, c_};                                                       \
    _Pragma("unroll")                                                          \
    for (int j=0;j<16;j++) S2[j] = a2*S2[j] + c2*k2_[j];                       \
    f32x2 oA={0.f,0.f},oB={0.f,0.f},oC={0.f,0.f},oD={0.f,0.f};                 \
    _Pragma("unroll")                                                          \
    for (int j=0;j<16;j+=4){                                                   \
      oA += S2[j+0]*q2_[j+0]; oB += S2[j+1]*q2_[j+1];                          \
      oC += S2[j+2]*q2_[j+2]; oD += S2[j+3]*q2_[j+3]; }                        \
    f32x2 oo = (oA+oB)+(oC+oD);                                                \
    Of[S][lane] = oo.x + oo.y;                                                 \
  } while(0)

  #define COMBINE(BUF,T0) do {                                                 \
    _Pragma("unroll")                                                          \
    for (int i=0;i<16;i++){                                                    \
      int idx = i*64 + lane;                                                   \
      int s_ = idx >> 5, c_ = idx & 31;                                        \
      float fv = Of[s_][c_];                                                   \
      float sv = Of[s_][c_+32];                                                \
      float gv = Bg[BUF][1][s_];                                               \
      qb[(size_t)((T0)+s_)*LDX + c_] = (f16)(gv*fv + (1.0f-gv)*sv);            \
    }                                                                          \
  } while(0)

  LOADG(0);
  STAGE(0);
  __syncthreads();

  float4 kA[8], qA[8], kB[8], qB[8];
  float vA, bA, vB, bB;

  for (int tile=0; tile<SS/TB; tile++){
    int buf = tile & 1;
    if (tile < SS/TB-1) LOADG((tile+1)*TB);
    LDSTEP(buf, 0, kA, qA, vA, bA);
    #pragma unroll
    for (int s=0; s<TB; s+=2){
      if (s+1 < TB) LDSTEP(buf, s+1, kB, qB, vB, bB);
      STEP(kA, qA, vA, bA, s);
      if (s+2 < TB) LDSTEP(buf, s+2, kA, qA, vA, bA);
      STEP(kB, qB, vB, bB, s+1);
    }
    if (tile < SS/TB-1) STAGE(1-buf);
    COMBINE(buf, tile*TB);
    __syncthreads();
  }
  #undef LOADG
  #undef STAGE
  #undef LDSTEP
  #undef STEP
  #undef COMBINE
}

// ---------------- masked mean-pool + L2 normalize ----------------
__global__ __launch_bounds__(384) void pool_kernel(
    const float* __restrict__ x, const int* __restrict__ mask, float* __restrict__ out)
{
  __shared__ float red[384];
  __shared__ float tot;
  int b = blockIdx.x, d = threadIdx.x;
  const float* xb = x + (size_t)b*SS*DD;
  const int* mb = mask + b*SS;
  float s=0.f, sm=0.f;
  for (int t=0;t<SS;t++){ float m=(float)mb[t]; s += xb[(size_t)t*DD+d]*m; sm += m; }
  float emb = s / fmaxf(sm, 1e-9f);
  red[d] = emb*emb;
  __syncthreads();
  for (int off=192; off>=3; off>>=1){
    if (d < off) red[d] += red[d+off];
    __syncthreads();
  }
  if (d==0) tot = red[0]+red[1]+red[2];
  __syncthreads();
  out[(size_t)b*DD + d] = emb * rsqrtf(tot);
}

extern "C" void kernel_launch(void* const* d_in, const int* in_sizes, int n_in,
                              void* d_out, int out_size, void* d_ws, size_t ws_size,
                              hipStream_t stream)
{
  const int*   ids  = (const int*)d_in[0];
  const int*   amask= (const int*)d_in[1];
  const float* we   = (const float*)d_in[2];
  const float* pe   = (const float*)d_in[3];
  const float* te   = (const float*)d_in[4];
  const float* elnw = (const float*)d_in[5];
  const float* elnb = (const float*)d_in[6];
  const float* Wq   = (const float*)d_in[7];
  const float* bq   = (const float*)d_in[8];
  const float* Wk   = (const float*)d_in[9];
  const float* bk   = (const float*)d_in[10];
  const float* Wv   = (const float*)d_in[11];
  const float* bv   = (const float*)d_in[12];
  const float* Wb   = (const float*)d_in[13];
  const float* bb   = (const float*)d_in[14];
  const float* Wg   = (const float*)d_in[15];
  const float* bgp  = (const float*)d_in[16];
  const float* Wo   = (const float*)d_in[17];
  const float* bo   = (const float*)d_in[18];
  const float* fl   = (const float*)d_in[19];
  const float* sl   = (const float*)d_in[20];
  const float* alnw = (const float*)d_in[21];
  const float* alnb = (const float*)d_in[22];
  const float* W1   = (const float*)d_in[23];
  const float* b1   = (const float*)d_in[24];
  const float* W2   = (const float*)d_in[25];
  const float* b2   = (const float*)d_in[26];
  const float* flnw = (const float*)d_in[27];
  const float* flnb = (const float*)d_in[28];
  float* out = (float*)d_out;
  float* w = (float*)d_ws;

  // workspace (float slots), total 49,355,520 f = 197.4 MB
  // x    [0, 12.58M f)           : residual f32
  // xh   [12.58M, 18.87M f)      : x as f16; FFN2 f16 output reuses this buffer
  // qkvh [18.87M, 37.75M f)      : qkv rows [32768][1152] f16
  // f2   [37.75M, 44.04M f)      : tail of full-M hidden; beta/gbuf live here
  //                                (attention phase only — temporally disjoint)
  // hidden full-M = qkvh+f2 = 50,331,648 h == 32768*1536 exactly
  // wt   [44.04M, 49.35M f)      : transposed f16 weights (6 layers)
  float* x    = w;                      // 12,582,912 f
  f16*  xh   = (f16*)(w + 12582912);    // 12,582,912 h
  f16*  qkvh = (f16*)(w + 18874368);    // 37,748,736 h  [row][1152]
  float* f2   = w + 37748736;           //  6,291,456 f region
  float* beta = f2 + 3145728;           //    393,216 f
  float* gbuf = beta + 393216;          //    393,216 f
  f16*  wt   = (f16*)(w + 44040192);    // 10,616,832 h (all 6 layers)
  float* bqkv = w + 49348608;           //      6,912 f
  f16*  hb   = qkvh;                    // full-M FFN hidden [32768][1536] h (overlays qkvh+f2)

  embed_ln_kernel<<<MROWS/4, 256, 0, stream>>>(ids, we, pe, te, elnw, elnb, x, xh);
  biaspack_kernel<<<27,256,0,stream>>>(bq, bk, bv, bqkv);
  wtrans_kernel<<<LL*1728,256,0,stream>>>(Wq, Wk, Wv, Wo, W1, W2, wt);

  for (int l=0;l<LL;l++){
    f16* wl = wt + (size_t)l*1769472;

    // fused QKV: [32768 x 1152] = xh @ [Wq|Wk|Wv]^T
    gemm_f16<0,1><<<dim3(9,256),256,0,stream>>>(xh, wl, bqkv + l*LDX, nullptr, qkvh,
                                                MROWS, LDX, DD, DD, LDX);

    betag_kernel<<<MROWS/4,256,0,stream>>>(x, Wb + (size_t)l*DD*HH, bb + l*HH,
                                           Wg + (size_t)l*DD*HH, bgp + l*HH,
                                           amask, beta, gbuf);
    scan_kernel<<<BB*HH,64,0,stream>>>(qkvh, beta, gbuf, fl + l*HH, sl + l*HH);

    // o-proj full-M: A = attn-out = qkv[:,0:384] (lda=1152), C(f16) -> dead k-slot qkv[:,384:768]
    gemm_f16<0,1><<<dim3(3,256),256,0,stream>>>(qkvh, wl+442368, bo+l*DD, nullptr,
                                                qkvh + 384, MROWS, DD, DD, LDX, LDX);
    add_ln_kernel<1><<<MROWS/4,256,0,stream>>>(x, xh, qkvh + 384, alnw+l*DD, alnb+l*DD, 0, LDX);

    // FFN full-M (hidden overlays qkvh+f2 exactly; qkv dead after add_ln above).
    gemm_f16<1,1><<<dim3(12,256),256,0,stream>>>(xh, wl+589824, b1+l*FFF, nullptr, hb,
                                                 MROWS, FFF, DD, DD, FFF);
    gemm_f16<0,1><<<dim3(3,256),256,0,stream>>>(hb, wl+1179648, b2+l*DD, nullptr, xh,
                                                MROWS, DD, FFF, FFF, DD);
    add_ln_kernel<1><<<MROWS/4,256,0,stream>>>(x, xh, xh, flnw+l*DD, flnb+l*DD, 0, DD);
  }

  pool_kernel<<<BB,384,0,stream>>>(x, amask, out);
}

// Round 6
// 3219.670 us; speedup vs baseline: 1.1169x; 1.0478x over previous
//
#include <hip/hip_runtime.h>
#include <math.h>

#define DD 384
#define HH 12
#define DKK 32
#define LL 6
#define FFF 1536
#define BB 64
#define SS 512
#define MROWS (BB*SS)   // 32768
#define TB 32           // scan time-tile
#define LDX 1152        // qkv row stride

typedef _Float16 f16;
typedef _Float16 half8 __attribute__((ext_vector_type(8)));
typedef _Float16 h2 __attribute__((ext_vector_type(2)));
typedef float f32x4 __attribute__((ext_vector_type(4)));
typedef float f32x2 __attribute__((ext_vector_type(2)));

__device__ __forceinline__ float sigmoidf_(float x){ return 1.0f/(1.0f+expf(-x)); }

__device__ __forceinline__ float h2f_lo(unsigned int u){
  union { unsigned short s; f16 h; } c; c.s = (unsigned short)(u & 0xffffu); return (float)c.h;
}
__device__ __forceinline__ float h2f_hi(unsigned int u){
  union { unsigned short s; f16 h; } c; c.s = (unsigned short)(u >> 16); return (float)c.h;
}

__device__ __forceinline__ void gl2lds16(const void* g, void* l){
  __builtin_amdgcn_global_load_lds((const __attribute__((address_space(1))) void*)g,
                                   (__attribute__((address_space(3))) void*)l, 16, 0, 0);
}

// betag fusion helper: given per-lane post-LN outputs o[6] (d = lane+64*i), weights
// staged in Ws[384*25] ([d][0:12]=Wb, [d][12:24]=Wg), compute beta/g for `row`.
// Bit-identical math to the old standalone betag kernel (same f32 inputs).
__device__ __forceinline__ void betag_tail(
    const float* Ws, const float o[6], int lane, int row,
    const float* __restrict__ bbq, const float* __restrict__ bgq,
    const int* __restrict__ mask, float* __restrict__ beta, float* __restrict__ g)
{
  float accb[12], accg[12];
  #pragma unroll
  for (int j=0;j<12;j++){ accb[j]=0.f; accg[j]=0.f; }
  #pragma unroll
  for (int i=0;i<6;i++){
    int k = lane + 64*i;
    float xv = o[i];
    const float* wr = &Ws[k*25];
    #pragma unroll
    for (int j=0;j<12;j++){ accb[j] += xv*wr[j]; accg[j] += xv*wr[12+j]; }
  }
  #pragma unroll
  for (int j=0;j<12;j++){
    #pragma unroll
    for (int off=32; off>=1; off>>=1){
      accb[j]+=__shfl_xor(accb[j],off);
      accg[j]+=__shfl_xor(accg[j],off);
    }
  }
  if (lane==0){
    float mk = (float)mask[row];
    #pragma unroll
    for (int j=0;j<12;j++){
      beta[(size_t)row*HH + j] = sigmoidf_(accb[j]+bbq[j]) * mk;
      g[(size_t)row*HH + j]    = sigmoidf_(accg[j]+bgq[j]);
    }
  }
}

__device__ __forceinline__ void betag_stage(
    float* Ws, const float* __restrict__ Wbp, const float* __restrict__ Wgp)
{
  for (int idx = threadIdx.x; idx < 384*12; idx += 256){
    int k = idx/12, j = idx - k*12;
    Ws[k*25+j]    = Wbp[idx];
    Ws[k*25+12+j] = Wgp[idx];
  }
  __syncthreads();
}

// ---------------- embedding + LN (writes fp32 x and f16 xh); fuses layer-0 betag ----------------
__global__ __launch_bounds__(256) void embed_ln_kernel(
    const int* __restrict__ ids, const float* __restrict__ we,
    const float* __restrict__ pe, const float* __restrict__ te,
    const float* __restrict__ w, const float* __restrict__ b,
    float* __restrict__ x, f16* __restrict__ xh,
    const float* __restrict__ Wbp, const float* __restrict__ bbq,
    const float* __restrict__ Wgp, const float* __restrict__ bgq,
    const int* __restrict__ mask, float* __restrict__ beta, float* __restrict__ g)
{
  extern __shared__ float Ws[];
  betag_stage(Ws, Wbp, Wgp);
  int wv = threadIdx.x >> 6, lane = threadIdx.x & 63;
  int row = blockIdx.x * 4 + wv;
  int s = row & (SS-1);
  int id = ids[row];
  const float* wep = we + (size_t)id * DD;
  const float* pep = pe + (size_t)s * DD;
  float vals[6]; float sum = 0.f;
  #pragma unroll
  for (int i=0;i<6;i++){ int d = lane + 64*i; vals[i] = wep[d] + pep[d] + te[d]; sum += vals[i]; }
  #pragma unroll
  for (int off=32; off>=1; off>>=1) sum += __shfl_xor(sum, off);
  float mean = sum * (1.0f/DD);
  float vs = 0.f;
  #pragma unroll
  for (int i=0;i<6;i++){ float dv = vals[i]-mean; vs += dv*dv; }
  #pragma unroll
  for (int off=32; off>=1; off>>=1) vs += __shfl_xor(vs, off);
  float inv = rsqrtf(vs*(1.0f/DD) + 1e-12f);
  float* xr = x + (size_t)row*DD;
  f16* xhr = xh + (size_t)row*DD;
  #pragma unroll
  for (int i=0;i<6;i++){ int d = lane + 64*i; float o = (vals[i]-mean)*inv*w[d] + b[d]; xr[d]=o; xhr[d]=(f16)o; vals[i]=o; }
  betag_tail(Ws, vals, lane, row, bbq, bgq, mask, beta, g);
}

// ---------------- x = LN(x + y); optionally fuses next layer's betag (BG=1) ----------------
// y f32 (YH=0) or f16 (YH=1), stride ldy. BG=1 requires 38400 B dynamic LDS.
template<int YH, int BG>
__global__ __launch_bounds__(256) void add_ln_kernel(
    float* __restrict__ x, f16* __restrict__ xh, const void* __restrict__ yp,
    const float* __restrict__ w, const float* __restrict__ b, int row0, int ldy,
    const float* __restrict__ Wbp, const float* __restrict__ bbq,
    const float* __restrict__ Wgp, const float* __restrict__ bgq,
    const int* __restrict__ mask, float* __restrict__ beta, float* __restrict__ g)
{
  extern __shared__ float Ws[];
  if (BG) betag_stage(Ws, Wbp, Wgp);
  int wv = threadIdx.x >> 6, lane = threadIdx.x & 63;
  int rrel = blockIdx.x * 4 + wv;
  int row = row0 + rrel;
  float* xr = x + (size_t)row*DD;
  f16* xhr = xh + (size_t)row*DD;
  float vals[6]; float sum = 0.f;
  #pragma unroll
  for (int i=0;i<6;i++){
    int d = lane + 64*i;
    float yv;
    if (YH) yv = (float)((const f16*)yp)[(size_t)rrel*ldy + d];
    else    yv = ((const float*)yp)[(size_t)rrel*ldy + d];
    vals[i] = xr[d] + yv; sum += vals[i];
  }
  #pragma unroll
  for (int off=32; off>=1; off>>=1) sum += __shfl_xor(sum, off);
  float mean = sum * (1.0f/DD);
  float vs = 0.f;
  #pragma unroll
  for (int i=0;i<6;i++){ float dv = vals[i]-mean; vs += dv*dv; }
  #pragma unroll
  for (int off=32; off>=1; off>>=1) vs += __shfl_xor(vs, off);
  float inv = rsqrtf(vs*(1.0f/DD) + 1e-12f);
  #pragma unroll
  for (int i=0;i<6;i++){ int d = lane + 64*i; float o = (vals[i]-mean)*inv*w[d] + b[d]; xr[d]=o; xhr[d]=(f16)o; vals[i]=o; }
  if (BG) betag_tail(Ws, vals, lane, row, bbq, bgq, mask, beta, g);
}

// ---------------- bias pack: [bq;bk;bv] per layer -> 1152 each ----------------
__global__ __launch_bounds__(256) void biaspack_kernel(
    const float* __restrict__ bq, const float* __restrict__ bk, const float* __restrict__ bv,
    float* __restrict__ dst)
{
  int i = blockIdx.x*256 + threadIdx.x;   // 6912 total
  if (i >= LL*LDX) return;
  int l = i / LDX, r = i - l*LDX;
  float v;
  if (r < 384) v = bq[l*DD + r];
  else if (r < 768) v = bk[l*DD + r-384];
  else v = bv[l*DD + r-768];
  dst[i] = v;
}

// ---------------- weight transpose + f32->f16, ALL layers in one dispatch ----------------
__global__ __launch_bounds__(256) void wtrans_kernel(
  const float* __restrict__ Wq, const float* __restrict__ Wk, const float* __restrict__ Wv,
  const float* __restrict__ Wo, const float* __restrict__ W1, const float* __restrict__ W2,
  f16* __restrict__ Wt)
{
  __shared__ float T[32][33];
  int l = blockIdx.x / 1728, bidx = blockIdx.x % 1728;
  const float* src; f16* dst; int K, N, tile;
  if (bidx < 576){ int m = bidx/144; tile = bidx - m*144; K=384; N=384;
    const float* w4[4] = {Wq + (size_t)l*147456, Wk + (size_t)l*147456,
                          Wv + (size_t)l*147456, Wo + (size_t)l*147456};
    src = w4[m]; dst = Wt + (size_t)l*1769472 + m*147456; }
  else if (bidx < 1152){ tile = bidx-576; K=384; N=1536;
    src = W1 + (size_t)l*589824; dst = Wt + (size_t)l*1769472 + 589824; }
  else { tile = bidx-1152; K=1536; N=384;
    src = W2 + (size_t)l*589824; dst = Wt + (size_t)l*1769472 + 1179648; }
  int tN = N>>5;
  int tk = tile / tN, tn = tile - tk*tN;
  int k0 = tk<<5, n0 = tn<<5;
  int r = threadIdx.x >> 3, c4 = (threadIdx.x & 7) << 2;
  float4 vv = *(const float4*)(src + (size_t)(k0+r)*N + n0 + c4);
  T[r][c4+0]=vv.x; T[r][c4+1]=vv.y; T[r][c4+2]=vv.z; T[r][c4+3]=vv.w;
  __syncthreads();
  f16* dp = dst + (size_t)(n0+r)*K + k0 + c4;
  #pragma unroll
  for (int j=0;j<4;j++) dp[j] = (f16)T[c4+j][r];
}

// ---------------- f16 MFMA GEMM, BK=64, double-buffered 2-phase ----------------
// Double-buffered LDS (64 KB, 2 blocks/CU), prefetch next K-tile BEFORE computing
// current, ONE barrier per K-step. Bijective chunked XCD swizzle (grids all %8==0).
// Per catalog, this 128^2 2-phase structure is at its ceiling (m99/m100/m131-141);
// next step would be the 256^2 8-phase port.
template<int ACT, int OUT16>
__global__ __launch_bounds__(256) void gemm_f16(
    const f16* __restrict__ A, const f16* __restrict__ BT,
    const float* __restrict__ bias, float* __restrict__ Cf, f16* __restrict__ Ch,
    int M, int N, int K, int lda, int ldc)
{
  __shared__ __align__(16) f16 As[2][2][128*32];
  __shared__ __align__(16) f16 Bs[2][2][128*32];
  int tid = threadIdx.x, lane = tid & 63, wave = tid >> 6;
  int wm = wave >> 1, wn = wave & 1;
  int gx = gridDim.x, gy = gridDim.y;
  int bid = blockIdx.y * gx + blockIdx.x;
  int chunk = (gx * gy) >> 3;
  int nf = (bid & 7) * chunk + (bid >> 3);
  int tx = nf / gy, ty = nf - tx * gy;
  int n0 = tx * 128, m0 = ty * 128;
  f32x4 acc[4][4] = {};
  int seg0 = wave*2048 + lane*16;
  int ar = lane & 15, kq = (lane >> 4) * 8;

  #define GSTAGE(PB, K0) do {                                                  \
    _Pragma("unroll")                                                          \
    for (int i=0;i<2;i++){                                                     \
      int seg = seg0 + i*1024;                                                 \
      int e = seg >> 1; int row = e >> 5; int kk = e & 31;                     \
      const f16* ap = A  + (size_t)(m0+row)*lda + (K0) + kk;                   \
      const f16* bp = BT + (size_t)(n0+row)*K   + (K0) + kk;                   \
      gl2lds16(ap,      (char*)As[PB][0] + seg);                               \
      gl2lds16(ap + 32, (char*)As[PB][1] + seg);                               \
      gl2lds16(bp,      (char*)Bs[PB][0] + seg);                               \
      gl2lds16(bp + 32, (char*)Bs[PB][1] + seg);                               \
    }                                                                          \
  } while(0)

  GSTAGE(0, 0);
  __syncthreads();
  int nk = K >> 6;
  int pb = 0;
  for (int t=0; t<nk; t++){
    if (t+1 < nk) GSTAGE(pb^1, (t+1)*64);
    #pragma unroll
    for (int h=0; h<2; h++){
      half8 af[4], bfr[4];
      #pragma unroll
      for (int mi=0;mi<4;mi++) af[mi]  = *(const half8*)&As[pb][h][(wm*64 + mi*16 + ar)*32 + kq];
      #pragma unroll
      for (int ni=0;ni<4;ni++) bfr[ni] = *(const half8*)&Bs[pb][h][(wn*64 + ni*16 + ar)*32 + kq];
      #pragma unroll
      for (int mi=0;mi<4;mi++)
        #pragma unroll
        for (int ni=0;ni<4;ni++)
          acc[mi][ni] = __builtin_amdgcn_mfma_f32_16x16x32_f16(af[mi], bfr[ni], acc[mi][ni], 0, 0, 0);
    }
    __syncthreads();   // drains prefetch vmcnt + guards buffer swap (one barrier/K-step)
    pb ^= 1;
  }
  #undef GSTAGE

  int rb = (lane >> 4) * 4, cb = lane & 15;
  #pragma unroll
  for (int ni=0;ni<4;ni++){
    int cn = n0 + wn*64 + ni*16 + cb;
    float bz = bias[cn];
    #pragma unroll
    for (int mi=0;mi<4;mi++){
      int rm = m0 + wm*64 + mi*16 + rb;
      #pragma unroll
      for (int r=0;r<4;r++){
        float v = acc[mi][ni][r] + bz;
        if (ACT==1) v = 0.5f*v*(1.0f+erff(v*0.70710678118f));
        if (OUT16) Ch[(size_t)(rm+r)*ldc + cn] = (f16)v;
        else       Cf[(size_t)(rm+r)*ldc + cn] = v;
      }
    }
  }
}

// ---------------- DeltaNet dual-state scan (R6 config: f32 LDS + packed f32x2 math) ----------------
// R6 config retained. Measured 153-155 us across sessions (R3's 198 was clock variance).
// R10 (4-wave) and R11 (k-half) restructures both regressed. Structurally frozen:
// parallelism = 2 states x 32 cols = 64 lanes exactly; sequential over S=512.
__global__ __launch_bounds__(64) void scan_kernel(
  f16* qkv,
  const float* __restrict__ bp, const float* __restrict__ gp,
  const float* __restrict__ flp, const float* __restrict__ slp)
{
  __shared__ float Kf[2][TB][32];
  __shared__ float Qf[2][TB][32];
  __shared__ float Vf[2][TB][32];
  __shared__ float Bg[2][2][TB];
  __shared__ float Of[TB][64];
  int blk = blockIdx.x;
  int b = blk / HH, h = blk - b*HH;
  int lane = threadIdx.x;
  int col = lane & 31;
  float a = sigmoidf_((lane < 32) ? flp[h] : slp[h]);
  f32x2 a2 = {a, a};
  f32x2 S2[16];
  #pragma unroll
  for (int j=0;j<16;j++) S2[j] = (f32x2){0.f,0.f};
  size_t base = ((size_t)b*SS)*LDX + (size_t)h*DKK;
  f16* qb = qkv + base;
  const f16* kb = qkv + base + 384;
  const f16* vb = qkv + base + 768;
  const float* bbp = bp + ((size_t)b*SS)*HH + h;
  const float* gbp = gp + ((size_t)b*SS)*HH + h;

  int st0 = lane >> 2, part = lane & 3;
  uint4 kv[2], qv[2], vv[2]; float bgv;

  #define LOADG(T0) do {                                                       \
    _Pragma("unroll")                                                          \
    for (int r=0;r<2;r++){                                                     \
      int st = (T0) + r*16 + st0;                                              \
      size_t off = (size_t)st*LDX + part*8;                                    \
      kv[r] = *(const uint4*)(kb + off);                                       \
      qv[r] = *(const uint4*)(qb + off);                                       \
      vv[r] = *(const uint4*)(vb + off);                                       \
    }                                                                          \
    int tb_ = (T0) + (lane & 31);                                              \
    bgv = (lane < 32) ? bbp[(size_t)tb_*HH] : gbp[(size_t)tb_*HH];             \
  } while(0)

  #define STAGE(BUF) do {                                                      \
    _Pragma("unroll")                                                          \
    for (int r=0;r<2;r++){                                                     \
      int s = r*16 + st0;                                                      \
      float kf[8], qf[8], vf[8];                                               \
      kf[0]=h2f_lo(kv[r].x); kf[1]=h2f_hi(kv[r].x); kf[2]=h2f_lo(kv[r].y);     \
      kf[3]=h2f_hi(kv[r].y); kf[4]=h2f_lo(kv[r].z); kf[5]=h2f_hi(kv[r].z);     \
      kf[6]=h2f_lo(kv[r].w); kf[7]=h2f_hi(kv[r].w);                            \
      qf[0]=h2f_lo(qv[r].x); qf[1]=h2f_hi(qv[r].x); qf[2]=h2f_lo(qv[r].y);     \
      qf[3]=h2f_hi(qv[r].y); qf[4]=h2f_lo(qv[r].z); qf[5]=h2f_hi(qv[r].z);     \
      qf[6]=h2f_lo(qv[r].w); qf[7]=h2f_hi(qv[r].w);                            \
      vf[0]=h2f_lo(vv[r].x); vf[1]=h2f_hi(vv[r].x); vf[2]=h2f_lo(vv[r].y);     \
      vf[3]=h2f_hi(vv[r].y); vf[4]=h2f_lo(vv[r].z); vf[5]=h2f_hi(vv[r].z);     \
      vf[6]=h2f_lo(vv[r].w); vf[7]=h2f_hi(vv[r].w);                            \
      float ss = 0.f;                                                          \
      _Pragma("unroll")                                                        \
      for (int i=0;i<8;i++) ss += kf[i]*kf[i];                                 \
      ss += __shfl_xor(ss, 1); ss += __shfl_xor(ss, 2);                        \
      float sc = 1.0f/(sqrtf(ss)+1e-6f);                                       \
      float4 t;                                                                \
      t.x=kf[0]*sc; t.y=kf[1]*sc; t.z=kf[2]*sc; t.w=kf[3]*sc;                  \
      *(float4*)&Kf[BUF][s][part*8] = t;                                       \
      t.x=kf[4]*sc; t.y=kf[5]*sc; t.z=kf[6]*sc; t.w=kf[7]*sc;                  \
      *(float4*)&Kf[BUF][s][part*8+4] = t;                                     \
      t.x=qf[0]; t.y=qf[1]; t.z=qf[2]; t.w=qf[3];                              \
      *(float4*)&Qf[BUF][s][part*8] = t;                                       \
      t.x=qf[4]; t.y=qf[5]; t.z=qf[6]; t.w=qf[7];                              \
      *(float4*)&Qf[BUF][s][part*8+4] = t;                                     \
      t.x=vf[0]; t.y=vf[1]; t.z=vf[2]; t.w=vf[3];                              \
      *(float4*)&Vf[BUF][s][part*8] = t;                                       \
      t.x=vf[4]; t.y=vf[5]; t.z=vf[6]; t.w=vf[7];                              \
      *(float4*)&Vf[BUF][s][part*8+4] = t;                                     \
    }                                                                          \
    Bg[BUF][lane>>5][lane&31] = bgv;                                           \
  } while(0)

  #define LDSTEP(BUF,S,KR,QR,VT,BT) do {                                       \
    const float4* k4_ = (const float4*)&Kf[BUF][S][0];                         \
    const float4* q4_ = (const float4*)&Qf[BUF][S][0];                         \
    _Pragma("unroll")                                                          \
    for (int j=0;j<8;j++){ KR[j]=k4_[j]; QR[j]=q4_[j]; }                       \
    VT = Vf[BUF][S][col]; BT = Bg[BUF][0][S];                                  \
  } while(0)

  #define STEP(KR,QR,VT,BT,S) do {                                            \
    const f32x2* k2_ = (const f32x2*)KR;                                       \
    const f32x2* q2_ = (const f32x2*)QR;                                       \
    f32x2 rA={0.f,0.f},rB={0.f,0.f},rC={0.f,0.f},rD={0.f,0.f};                 \
    _Pragma("unroll")                                                          \
    for (int j=0;j<16;j+=4){                                                   \
      rA += S2[j+0]*k2_[j+0]; rB += S2[j+1]*k2_[j+1];                          \
      rC += S2[j+2]*k2_[j+2]; rD += S2[j+3]*k2_[j+3]; }                        \
    f32x2 rr = (rA+rB)+(rC+rD);                                                \
    float rf = rr.x + rr.y;                                                    \
    float c_ = (BT)*((VT) - rf);                                               \
    f32x2 c2 = {c_, c_};                                                       \
    _Pragma("unroll")                                                          \
    for (int j=0;j<16;j++) S2[j] = a2*S2[j] + c2*k2_[j];                       \
    f32x2 oA={0.f,0.f},oB={0.f,0.f},oC={0.f,0.f},oD={0.f,0.f};                 \
    _Pragma("unroll")                                                          \
    for (int j=0;j<16;j+=4){                                                   \
      oA += S2[j+0]*q2_[j+0]; oB += S2[j+1]*q2_[j+1];                          \
      oC += S2[j+2]*q2_[j+2]; oD += S2[j+3]*q2_[j+3]; }                        \
    f32x2 oo = (oA+oB)+(oC+oD);                                                \
    Of[S][lane] = oo.x + oo.y;                                                 \
  } while(0)

  #define COMBINE(BUF,T0) do {                                                 \
    _Pragma("unroll")                                                          \
    for (int i=0;i<16;i++){                                                    \
      int idx = i*64 + lane;                                                   \
      int s_ = idx >> 5, c_ = idx & 31;                                        \
      float fv = Of[s_][c_];                                                   \
      float sv = Of[s_][c_+32];                                                \
      float gv = Bg[BUF][1][s_];                                               \
      qb[(size_t)((T0)+s_)*LDX + c_] = (f16)(gv*fv + (1.0f-gv)*sv);            \
    }                                                                          \
  } while(0)

  LOADG(0);
  STAGE(0);
  __syncthreads();

  float4 kA[8], qA[8], kB[8], qB[8];
  float vA, bA, vB, bB;

  for (int tile=0; tile<SS/TB; tile++){
    int buf = tile & 1;
    if (tile < SS/TB-1) LOADG((tile+1)*TB);
    LDSTEP(buf, 0, kA, qA, vA, bA);
    #pragma unroll
    for (int s=0; s<TB; s+=2){
      if (s+1 < TB) LDSTEP(buf, s+1, kB, qB, vB, bB);
      STEP(kA, qA, vA, bA, s);
      if (s+2 < TB) LDSTEP(buf, s+2, kA, qA, vA, bA);
      STEP(kB, qB, vB, bB, s+1);
    }
    if (tile < SS/TB-1) STAGE(1-buf);
    COMBINE(buf, tile*TB);
    __syncthreads();
  }
  #undef LOADG
  #undef STAGE
  #undef LDSTEP
  #undef STEP
  #undef COMBINE
}

// ---------------- masked mean-pool + L2 normalize ----------------
__global__ __launch_bounds__(384) void pool_kernel(
    const float* __restrict__ x, const int* __restrict__ mask, float* __restrict__ out)
{
  __shared__ float red[384];
  __shared__ float tot;
  int b = blockIdx.x, d = threadIdx.x;
  const float* xb = x + (size_t)b*SS*DD;
  const int* mb = mask + b*SS;
  float s=0.f, sm=0.f;
  for (int t=0;t<SS;t++){ float m=(float)mb[t]; s += xb[(size_t)t*DD+d]*m; sm += m; }
  float emb = s / fmaxf(sm, 1e-9f);
  red[d] = emb*emb;
  __syncthreads();
  for (int off=192; off>=3; off>>=1){
    if (d < off) red[d] += red[d+off];
    __syncthreads();
  }
  if (d==0) tot = red[0]+red[1]+red[2];
  __syncthreads();
  out[(size_t)b*DD + d] = emb * rsqrtf(tot);
}

extern "C" void kernel_launch(void* const* d_in, const int* in_sizes, int n_in,
                              void* d_out, int out_size, void* d_ws, size_t ws_size,
                              hipStream_t stream)
{
  const int*   ids  = (const int*)d_in[0];
  const int*   amask= (const int*)d_in[1];
  const float* we   = (const float*)d_in[2];
  const float* pe   = (const float*)d_in[3];
  const float* te   = (const float*)d_in[4];
  const float* elnw = (const float*)d_in[5];
  const float* elnb = (const float*)d_in[6];
  const float* Wq   = (const float*)d_in[7];
  const float* bq   = (const float*)d_in[8];
  const float* Wk   = (const float*)d_in[9];
  const float* bk   = (const float*)d_in[10];
  const float* Wv   = (const float*)d_in[11];
  const float* bv   = (const float*)d_in[12];
  const float* Wb   = (const float*)d_in[13];
  const float* bb   = (const float*)d_in[14];
  const float* Wg   = (const float*)d_in[15];
  const float* bgp  = (const float*)d_in[16];
  const float* Wo   = (const float*)d_in[17];
  const float* bo   = (const float*)d_in[18];
  const float* fl   = (const float*)d_in[19];
  const float* sl   = (const float*)d_in[20];
  const float* alnw = (const float*)d_in[21];
  const float* alnb = (const float*)d_in[22];
  const float* W1   = (const float*)d_in[23];
  const float* b1   = (const float*)d_in[24];
  const float* W2   = (const float*)d_in[25];
  const float* b2   = (const float*)d_in[26];
  const float* flnw = (const float*)d_in[27];
  const float* flnb = (const float*)d_in[28];
  float* out = (float*)d_out;
  float* w = (float*)d_ws;

  // workspace (float slots), total 49,355,520 f = 197.4 MB
  // x    [0, 12.58M f)           : residual f32
  // xh   [12.58M, 18.87M f)      : x as f16; FFN2 f16 output reuses this buffer
  // qkvh [18.87M, 37.75M f)      : qkv rows [32768][1152] f16
  // f2   [37.75M, 44.04M f)      : tail of full-M hidden; beta/gbuf live here.
  //   Lifetime: beta(l)/g(l) written by ffn-add_ln(l-1) (or embed_ln for l=0),
  //   consumed by scan(l) (QKV(l) touches qkvh only), clobbered by FFN1(l) after.
  // wt   [44.04M, 49.35M f)      : transposed f16 weights (6 layers)
  float* x    = w;                      // 12,582,912 f
  f16*  xh   = (f16*)(w + 12582912);    // 12,582,912 h
  f16*  qkvh = (f16*)(w + 18874368);    // 37,748,736 h  [row][1152]
  float* f2   = w + 37748736;           //  6,291,456 f region
  float* beta = f2 + 3145728;           //    393,216 f
  float* gbuf = beta + 393216;          //    393,216 f
  f16*  wt   = (f16*)(w + 44040192);    // 10,616,832 h (all 6 layers)
  float* bqkv = w + 49348608;           //      6,912 f
  f16*  hb   = qkvh;                    // full-M FFN hidden [32768][1536] h (overlays qkvh+f2)

  const size_t BGLDS = 384*25*sizeof(float);   // 38400 B dynamic LDS for fused betag

  embed_ln_kernel<<<MROWS/4, 256, BGLDS, stream>>>(ids, we, pe, te, elnw, elnb, x, xh,
                                                   Wb, bb, Wg, bgp, amask, beta, gbuf);
  biaspack_kernel<<<27,256,0,stream>>>(bq, bk, bv, bqkv);
  wtrans_kernel<<<LL*1728,256,0,stream>>>(Wq, Wk, Wv, Wo, W1, W2, wt);

  for (int l=0;l<LL;l++){
    f16* wl = wt + (size_t)l*1769472;

    // fused QKV: [32768 x 1152] = xh @ [Wq|Wk|Wv]^T
    gemm_f16<0,1><<<dim3(9,256),256,0,stream>>>(xh, wl, bqkv + l*LDX, nullptr, qkvh,
                                                MROWS, LDX, DD, DD, LDX);

    // beta/g for this layer were computed by the previous layer's ffn-add_ln (or embed_ln)
    scan_kernel<<<BB*HH,64,0,stream>>>(qkvh, beta, gbuf, fl + l*HH, sl + l*HH);

    // o-proj full-M: A = attn-out = qkv[:,0:384] (lda=1152), C(f16) -> dead k-slot qkv[:,384:768]
    gemm_f16<0,1><<<dim3(3,256),256,0,stream>>>(qkvh, wl+442368, bo+l*DD, nullptr,
                                                qkvh + 384, MROWS, DD, DD, LDX, LDX);
    add_ln_kernel<1,0><<<MROWS/4,256,0,stream>>>(x, xh, qkvh + 384, alnw+l*DD, alnb+l*DD, 0, LDX,
                                                 nullptr, nullptr, nullptr, nullptr,
                                                 nullptr, nullptr, nullptr);

    // FFN full-M (hidden overlays qkvh+f2 exactly; qkv dead after add_ln above).
    gemm_f16<1,1><<<dim3(12,256),256,0,stream>>>(xh, wl+589824, b1+l*FFF, nullptr, hb,
                                                 MROWS, FFF, DD, DD, FFF);
    gemm_f16<0,1><<<dim3(3,256),256,0,stream>>>(hb, wl+1179648, b2+l*DD, nullptr, xh,
                                                MROWS, DD, FFF, FFF, DD);
    // ffn add_ln; for l<5 fuse betag of layer l+1 (x rows are live in registers here)
    if (l < LL-1)
      add_ln_kernel<1,1><<<MROWS/4,256,BGLDS,stream>>>(x, xh, xh, flnw+l*DD, flnb+l*DD, 0, DD,
                                                       Wb + (size_t)(l+1)*DD*HH, bb + (l+1)*HH,
                                                       Wg + (size_t)(l+1)*DD*HH, bgp + (l+1)*HH,
                                                       amask, beta, gbuf);
    else
      add_ln_kernel<1,0><<<MROWS/4,256,0,stream>>>(x, xh, xh, flnw+l*DD, flnb+l*DD, 0, DD,
                                                   nullptr, nullptr, nullptr, nullptr,
                                                   nullptr, nullptr, nullptr);
  }

  pool_kernel<<<BB,384,0,stream>>>(x, amask, out);
}

// Round 7
// 2956.111 us; speedup vs baseline: 1.2165x; 1.0892x over previous
//
#include <hip/hip_runtime.h>
#include <math.h>

#define DD 384
#define HH 12
#define DKK 32
#define LL 6
#define FFF 1536
#define BB 64
#define SS 512
#define MROWS (BB*SS)   // 32768
#define TB 32           // scan time-tile
#define LDX 1152        // qkv row stride

typedef _Float16 f16;
typedef _Float16 half8 __attribute__((ext_vector_type(8)));
typedef _Float16 h2 __attribute__((ext_vector_type(2)));
typedef float f32x4 __attribute__((ext_vector_type(4)));
typedef float f32x2 __attribute__((ext_vector_type(2)));

__device__ __forceinline__ float sigmoidf_(float x){ return 1.0f/(1.0f+expf(-x)); }

__device__ __forceinline__ float h2f_lo(unsigned int u){
  union { unsigned short s; f16 h; } c; c.s = (unsigned short)(u & 0xffffu); return (float)c.h;
}
__device__ __forceinline__ float h2f_hi(unsigned int u){
  union { unsigned short s; f16 h; } c; c.s = (unsigned short)(u >> 16); return (float)c.h;
}

__device__ __forceinline__ void gl2lds16(const void* g, void* l){
  __builtin_amdgcn_global_load_lds((const __attribute__((address_space(1))) void*)g,
                                   (__attribute__((address_space(3))) void*)l, 16, 0, 0);
}

// betag fusion helper: given per-lane post-LN outputs o[6] (d = lane+64*i), weights
// staged in Ws[384*25] ([d][0:12]=Wb, [d][12:24]=Wg), compute beta/g for `row`.
// Bit-identical math to the old standalone betag kernel (same f32 inputs).
__device__ __forceinline__ void betag_tail(
    const float* Ws, const float o[6], int lane, int row,
    const float* __restrict__ bbq, const float* __restrict__ bgq,
    const int* __restrict__ mask, float* __restrict__ beta, float* __restrict__ g)
{
  float accb[12], accg[12];
  #pragma unroll
  for (int j=0;j<12;j++){ accb[j]=0.f; accg[j]=0.f; }
  #pragma unroll
  for (int i=0;i<6;i++){
    int k = lane + 64*i;
    float xv = o[i];
    const float* wr = &Ws[k*25];
    #pragma unroll
    for (int j=0;j<12;j++){ accb[j] += xv*wr[j]; accg[j] += xv*wr[12+j]; }
  }
  #pragma unroll
  for (int j=0;j<12;j++){
    #pragma unroll
    for (int off=32; off>=1; off>>=1){
      accb[j]+=__shfl_xor(accb[j],off);
      accg[j]+=__shfl_xor(accg[j],off);
    }
  }
  if (lane==0){
    float mk = (float)mask[row];
    #pragma unroll
    for (int j=0;j<12;j++){
      beta[(size_t)row*HH + j] = sigmoidf_(accb[j]+bbq[j]) * mk;
      g[(size_t)row*HH + j]    = sigmoidf_(accg[j]+bgq[j]);
    }
  }
}

__device__ __forceinline__ void betag_stage(
    float* Ws, const float* __restrict__ Wbp, const float* __restrict__ Wgp)
{
  for (int idx = threadIdx.x; idx < 384*12; idx += 256){
    int k = idx/12, j = idx - k*12;
    Ws[k*25+j]    = Wbp[idx];
    Ws[k*25+12+j] = Wgp[idx];
  }
  __syncthreads();
}

// ---------------- embedding + LN (writes fp32 x and f16 xh); fuses layer-0 betag ----------------
__global__ __launch_bounds__(256) void embed_ln_kernel(
    const int* __restrict__ ids, const float* __restrict__ we,
    const float* __restrict__ pe, const float* __restrict__ te,
    const float* __restrict__ w, const float* __restrict__ b,
    float* __restrict__ x, f16* __restrict__ xh,
    const float* __restrict__ Wbp, const float* __restrict__ bbq,
    const float* __restrict__ Wgp, const float* __restrict__ bgq,
    const int* __restrict__ mask, float* __restrict__ beta, float* __restrict__ g)
{
  extern __shared__ float Ws[];
  betag_stage(Ws, Wbp, Wgp);
  int wv = threadIdx.x >> 6, lane = threadIdx.x & 63;
  int row = blockIdx.x * 4 + wv;
  int s = row & (SS-1);
  int id = ids[row];
  const float* wep = we + (size_t)id * DD;
  const float* pep = pe + (size_t)s * DD;
  float vals[6]; float sum = 0.f;
  #pragma unroll
  for (int i=0;i<6;i++){ int d = lane + 64*i; vals[i] = wep[d] + pep[d] + te[d]; sum += vals[i]; }
  #pragma unroll
  for (int off=32; off>=1; off>>=1) sum += __shfl_xor(sum, off);
  float mean = sum * (1.0f/DD);
  float vs = 0.f;
  #pragma unroll
  for (int i=0;i<6;i++){ float dv = vals[i]-mean; vs += dv*dv; }
  #pragma unroll
  for (int off=32; off>=1; off>>=1) vs += __shfl_xor(vs, off);
  float inv = rsqrtf(vs*(1.0f/DD) + 1e-12f);
  float* xr = x + (size_t)row*DD;
  f16* xhr = xh + (size_t)row*DD;
  #pragma unroll
  for (int i=0;i<6;i++){ int d = lane + 64*i; float o = (vals[i]-mean)*inv*w[d] + b[d]; xr[d]=o; xhr[d]=(f16)o; vals[i]=o; }
  betag_tail(Ws, vals, lane, row, bbq, bgq, mask, beta, g);
}

// ---------------- x = LN(x + y); optionally fuses next layer's betag (BG=1) ----------------
// y f32 (YH=0) or f16 (YH=1), stride ldy. BG=1 requires 38400 B dynamic LDS.
// WX=0 skips the xh store (final layer: nothing reads xh afterwards).
template<int YH, int BG, int WX>
__global__ __launch_bounds__(256) void add_ln_kernel(
    float* __restrict__ x, f16* __restrict__ xh, const void* __restrict__ yp,
    const float* __restrict__ w, const float* __restrict__ b, int row0, int ldy,
    const float* __restrict__ Wbp, const float* __restrict__ bbq,
    const float* __restrict__ Wgp, const float* __restrict__ bgq,
    const int* __restrict__ mask, float* __restrict__ beta, float* __restrict__ g)
{
  extern __shared__ float Ws[];
  if (BG) betag_stage(Ws, Wbp, Wgp);
  int wv = threadIdx.x >> 6, lane = threadIdx.x & 63;
  int rrel = blockIdx.x * 4 + wv;
  int row = row0 + rrel;
  float* xr = x + (size_t)row*DD;
  f16* xhr = xh + (size_t)row*DD;
  float vals[6]; float sum = 0.f;
  #pragma unroll
  for (int i=0;i<6;i++){
    int d = lane + 64*i;
    float yv;
    if (YH) yv = (float)((const f16*)yp)[(size_t)rrel*ldy + d];
    else    yv = ((const float*)yp)[(size_t)rrel*ldy + d];
    vals[i] = xr[d] + yv; sum += vals[i];
  }
  #pragma unroll
  for (int off=32; off>=1; off>>=1) sum += __shfl_xor(sum, off);
  float mean = sum * (1.0f/DD);
  float vs = 0.f;
  #pragma unroll
  for (int i=0;i<6;i++){ float dv = vals[i]-mean; vs += dv*dv; }
  #pragma unroll
  for (int off=32; off>=1; off>>=1) vs += __shfl_xor(vs, off);
  float inv = rsqrtf(vs*(1.0f/DD) + 1e-12f);
  #pragma unroll
  for (int i=0;i<6;i++){
    int d = lane + 64*i;
    float o = (vals[i]-mean)*inv*w[d] + b[d];
    xr[d]=o;
    if (WX) xhr[d]=(f16)o;
    vals[i]=o;
  }
  if (BG) betag_tail(Ws, vals, lane, row, bbq, bgq, mask, beta, g);
}

// ---------------- bias pack: [bq;bk;bv] per layer -> 1152 each ----------------
__global__ __launch_bounds__(256) void biaspack_kernel(
    const float* __restrict__ bq, const float* __restrict__ bk, const float* __restrict__ bv,
    float* __restrict__ dst)
{
  int i = blockIdx.x*256 + threadIdx.x;   // 6912 total
  if (i >= LL*LDX) return;
  int l = i / LDX, r = i - l*LDX;
  float v;
  if (r < 384) v = bq[l*DD + r];
  else if (r < 768) v = bk[l*DD + r-384];
  else v = bv[l*DD + r-768];
  dst[i] = v;
}

// ---------------- weight transpose + f32->f16, ALL layers in one dispatch ----------------
__global__ __launch_bounds__(256) void wtrans_kernel(
  const float* __restrict__ Wq, const float* __restrict__ Wk, const float* __restrict__ Wv,
  const float* __restrict__ Wo, const float* __restrict__ W1, const float* __restrict__ W2,
  f16* __restrict__ Wt)
{
  __shared__ float T[32][33];
  int l = blockIdx.x / 1728, bidx = blockIdx.x % 1728;
  const float* src; f16* dst; int K, N, tile;
  if (bidx < 576){ int m = bidx/144; tile = bidx - m*144; K=384; N=384;
    const float* w4[4] = {Wq + (size_t)l*147456, Wk + (size_t)l*147456,
                          Wv + (size_t)l*147456, Wo + (size_t)l*147456};
    src = w4[m]; dst = Wt + (size_t)l*1769472 + m*147456; }
  else if (bidx < 1152){ tile = bidx-576; K=384; N=1536;
    src = W1 + (size_t)l*589824; dst = Wt + (size_t)l*1769472 + 589824; }
  else { tile = bidx-1152; K=1536; N=384;
    src = W2 + (size_t)l*589824; dst = Wt + (size_t)l*1769472 + 1179648; }
  int tN = N>>5;
  int tk = tile / tN, tn = tile - tk*tN;
  int k0 = tk<<5, n0 = tn<<5;
  int r = threadIdx.x >> 3, c4 = (threadIdx.x & 7) << 2;
  float4 vv = *(const float4*)(src + (size_t)(k0+r)*N + n0 + c4);
  T[r][c4+0]=vv.x; T[r][c4+1]=vv.y; T[r][c4+2]=vv.z; T[r][c4+3]=vv.w;
  __syncthreads();
  f16* dp = dst + (size_t)(n0+r)*K + k0 + c4;
  #pragma unroll
  for (int j=0;j<4;j++) dp[j] = (f16)T[c4+j][r];
}

// ---------------- f16 MFMA GEMM, BK=64, double-buffered 2-phase ----------------
// Double-buffered LDS (64 KB, 2 blocks/CU), prefetch next K-tile BEFORE computing
// current, ONE barrier per K-step. Bijective chunked XCD swizzle.
// R14: tile enumeration flipped B-major -> A-major. For all GEMMs here B is tiny
// (<=1.1 MB, always L2-resident) while A is 25-100 MB; the old x-major order
// re-read A N/128 times (FFN2: 3 x 100 MB). A-major reuses each A row-panel across
// all gx n-tiles back-to-back and gives each XCD a disjoint M/8 slice -> A read once.
template<int ACT, int OUT16>
__global__ __launch_bounds__(256) void gemm_f16(
    const f16* __restrict__ A, const f16* __restrict__ BT,
    const float* __restrict__ bias, float* __restrict__ Cf, f16* __restrict__ Ch,
    int M, int N, int K, int lda, int ldc)
{
  __shared__ __align__(16) f16 As[2][2][128*32];
  __shared__ __align__(16) f16 Bs[2][2][128*32];
  int tid = threadIdx.x, lane = tid & 63, wave = tid >> 6;
  int wm = wave >> 1, wn = wave & 1;
  int gx = gridDim.x, gy = gridDim.y;
  int bid = blockIdx.y * gx + blockIdx.x;
  int chunk = (gx * gy) >> 3;
  int nf = (bid & 7) * chunk + (bid >> 3);
  int ty = nf / gx, tx = nf - ty * gx;   // A-panel-major: consecutive nf share ty
  int n0 = tx * 128, m0 = ty * 128;
  f32x4 acc[4][4] = {};
  int seg0 = wave*2048 + lane*16;
  int ar = lane & 15, kq = (lane >> 4) * 8;

  #define GSTAGE(PB, K0) do {                                                  \
    _Pragma("unroll")                                                          \
    for (int i=0;i<2;i++){                                                     \
      int seg = seg0 + i*1024;                                                 \
      int e = seg >> 1; int row = e >> 5; int kk = e & 31;                     \
      const f16* ap = A  + (size_t)(m0+row)*lda + (K0) + kk;                   \
      const f16* bp = BT + (size_t)(n0+row)*K   + (K0) + kk;                   \
      gl2lds16(ap,      (char*)As[PB][0] + seg);                               \
      gl2lds16(ap + 32, (char*)As[PB][1] + seg);                               \
      gl2lds16(bp,      (char*)Bs[PB][0] + seg);                               \
      gl2lds16(bp + 32, (char*)Bs[PB][1] + seg);                               \
    }                                                                          \
  } while(0)

  GSTAGE(0, 0);
  __syncthreads();
  int nk = K >> 6;
  int pb = 0;
  for (int t=0; t<nk; t++){
    if (t+1 < nk) GSTAGE(pb^1, (t+1)*64);
    #pragma unroll
    for (int h=0; h<2; h++){
      half8 af[4], bfr[4];
      #pragma unroll
      for (int mi=0;mi<4;mi++) af[mi]  = *(const half8*)&As[pb][h][(wm*64 + mi*16 + ar)*32 + kq];
      #pragma unroll
      for (int ni=0;ni<4;ni++) bfr[ni] = *(const half8*)&Bs[pb][h][(wn*64 + ni*16 + ar)*32 + kq];
      #pragma unroll
      for (int mi=0;mi<4;mi++)
        #pragma unroll
        for (int ni=0;ni<4;ni++)
          acc[mi][ni] = __builtin_amdgcn_mfma_f32_16x16x32_f16(af[mi], bfr[ni], acc[mi][ni], 0, 0, 0);
    }
    __syncthreads();   // drains prefetch vmcnt + guards buffer swap (one barrier/K-step)
    pb ^= 1;
  }
  #undef GSTAGE

  int rb = (lane >> 4) * 4, cb = lane & 15;
  #pragma unroll
  for (int ni=0;ni<4;ni++){
    int cn = n0 + wn*64 + ni*16 + cb;
    float bz = bias[cn];
    #pragma unroll
    for (int mi=0;mi<4;mi++){
      int rm = m0 + wm*64 + mi*16 + rb;
      #pragma unroll
      for (int r=0;r<4;r++){
        float v = acc[mi][ni][r] + bz;
        if (ACT==1) v = 0.5f*v*(1.0f+erff(v*0.70710678118f));
        if (OUT16) Ch[(size_t)(rm+r)*ldc + cn] = (f16)v;
        else       Cf[(size_t)(rm+r)*ldc + cn] = v;
      }
    }
  }
}

// ---------------- DeltaNet dual-state scan (R6 config: f32 LDS + packed f32x2 math) ----------------
// R6 config retained. Measured 153-155 us across sessions (R3's 198 was clock variance).
// R10 (4-wave) and R11 (k-half) restructures both regressed. Structurally frozen:
// parallelism = 2 states x 32 cols = 64 lanes exactly; sequential over S=512.
__global__ __launch_bounds__(64) void scan_kernel(
  f16* qkv,
  const float* __restrict__ bp, const float* __restrict__ gp,
  const float* __restrict__ flp, const float* __restrict__ slp)
{
  __shared__ float Kf[2][TB][32];
  __shared__ float Qf[2][TB][32];
  __shared__ float Vf[2][TB][32];
  __shared__ float Bg[2][2][TB];
  __shared__ float Of[TB][64];
  int blk = blockIdx.x;
  int b = blk / HH, h = blk - b*HH;
  int lane = threadIdx.x;
  int col = lane & 31;
  float a = sigmoidf_((lane < 32) ? flp[h] : slp[h]);
  f32x2 a2 = {a, a};
  f32x2 S2[16];
  #pragma unroll
  for (int j=0;j<16;j++) S2[j] = (f32x2){0.f,0.f};
  size_t base = ((size_t)b*SS)*LDX + (size_t)h*DKK;
  f16* qb = qkv + base;
  const f16* kb = qkv + base + 384;
  const f16* vb = qkv + base + 768;
  const float* bbp = bp + ((size_t)b*SS)*HH + h;
  const float* gbp = gp + ((size_t)b*SS)*HH + h;

  int st0 = lane >> 2, part = lane & 3;
  uint4 kv[2], qv[2], vv[2]; float bgv;

  #define LOADG(T0) do {                                                       \
    _Pragma("unroll")                                                          \
    for (int r=0;r<2;r++){                                                     \
      int st = (T0) + r*16 + st0;                                              \
      size_t off = (size_t)st*LDX + part*8;                                    \
      kv[r] = *(const uint4*)(kb + off);                                       \
      qv[r] = *(const uint4*)(qb + off);                                       \
      vv[r] = *(const uint4*)(vb + off);                                       \
    }                                                                          \
    int tb_ = (T0) + (lane & 31);                                              \
    bgv = (lane < 32) ? bbp[(size_t)tb_*HH] : gbp[(size_t)tb_*HH];             \
  } while(0)

  #define STAGE(BUF) do {                                                      \
    _Pragma("unroll")                                                          \
    for (int r=0;r<2;r++){                                                     \
      int s = r*16 + st0;                                                      \
      float kf[8], qf[8], vf[8];                                               \
      kf[0]=h2f_lo(kv[r].x); kf[1]=h2f_hi(kv[r].x); kf[2]=h2f_lo(kv[r].y);     \
      kf[3]=h2f_hi(kv[r].y); kf[4]=h2f_lo(kv[r].z); kf[5]=h2f_hi(kv[r].z);     \
      kf[6]=h2f_lo(kv[r].w); kf[7]=h2f_hi(kv[r].w);                            \
      qf[0]=h2f_lo(qv[r].x); qf[1]=h2f_hi(qv[r].x); qf[2]=h2f_lo(qv[r].y);     \
      qf[3]=h2f_hi(qv[r].y); qf[4]=h2f_lo(qv[r].z); qf[5]=h2f_hi(qv[r].z);     \
      qf[6]=h2f_lo(qv[r].w); qf[7]=h2f_hi(qv[r].w);                            \
      vf[0]=h2f_lo(vv[r].x); vf[1]=h2f_hi(vv[r].x); vf[2]=h2f_lo(vv[r].y);     \
      vf[3]=h2f_hi(vv[r].y); vf[4]=h2f_lo(vv[r].z); vf[5]=h2f_hi(vv[r].z);     \
      vf[6]=h2f_lo(vv[r].w); vf[7]=h2f_hi(vv[r].w);                            \
      float ss = 0.f;                                                          \
      _Pragma("unroll")                                                        \
      for (int i=0;i<8;i++) ss += kf[i]*kf[i];                                 \
      ss += __shfl_xor(ss, 1); ss += __shfl_xor(ss, 2);                        \
      float sc = 1.0f/(sqrtf(ss)+1e-6f);                                       \
      float4 t;                                                                \
      t.x=kf[0]*sc; t.y=kf[1]*sc; t.z=kf[2]*sc; t.w=kf[3]*sc;                  \
      *(float4*)&Kf[BUF][s][part*8] = t;                                       \
      t.x=kf[4]*sc; t.y=kf[5]*sc; t.z=kf[6]*sc; t.w=kf[7]*sc;                  \
      *(float4*)&Kf[BUF][s][part*8+4] = t;                                     \
      t.x=qf[0]; t.y=qf[1]; t.z=qf[2]; t.w=qf[3];                              \
      *(float4*)&Qf[BUF][s][part*8] = t;                                       \
      t.x=qf[4]; t.y=qf[5]; t.z=qf[6]; t.w=qf[7];                              \
      *(float4*)&Qf[BUF][s][part*8+4] = t;                                     \
      t.x=vf[0]; t.y=vf[1]; t.z=vf[2]; t.w=vf[3];                              \
      *(float4*)&Vf[BUF][s][part*8] = t;                                       \
      t.x=vf[4]; t.y=vf[5]; t.z=vf[6]; t.w=vf[7];                              \
      *(float4*)&Vf[BUF][s][part*8+4] = t;                                     \
    }                                                                          \
    Bg[BUF][lane>>5][lane&31] = bgv;                                           \
  } while(0)

  #define LDSTEP(BUF,S,KR,QR,VT,BT) do {                                       \
    const float4* k4_ = (const float4*)&Kf[BUF][S][0];                         \
    const float4* q4_ = (const float4*)&Qf[BUF][S][0];                         \
    _Pragma("unroll")                                                          \
    for (int j=0;j<8;j++){ KR[j]=k4_[j]; QR[j]=q4_[j]; }                       \
    VT = Vf[BUF][S][col]; BT = Bg[BUF][0][S];                                  \
  } while(0)

  #define STEP(KR,QR,VT,BT,S) do {                                            \
    const f32x2* k2_ = (const f32x2*)KR;                                       \
    const f32x2* q2_ = (const f32x2*)QR;                                       \
    f32x2 rA={0.f,0.f},rB={0.f,0.f},rC={0.f,0.f},rD={0.f,0.f};                 \
    _Pragma("unroll")                                                          \
    for (int j=0;j<16;j+=4){                                                   \
      rA += S2[j+0]*k2_[j+0]; rB += S2[j+1]*k2_[j+1];                          \
      rC += S2[j+2]*k2_[j+2]; rD += S2[j+3]*k2_[j+3]; }                        \
    f32x2 rr = (rA+rB)+(rC+rD);                                                \
    float rf = rr.x + rr.y;                                                    \
    float c_ = (BT)*((VT) - rf);                                               \
    f32x2 c2 = {c_, c_};                                                       \
    _Pragma("unroll")                                                          \
    for (int j=0;j<16;j++) S2[j] = a2*S2[j] + c2*k2_[j];                       \
    f32x2 oA={0.f,0.f},oB={0.f,0.f},oC={0.f,0.f},oD={0.f,0.f};                 \
    _Pragma("unroll")                                                          \
    for (int j=0;j<16;j+=4){                                                   \
      oA += S2[j+0]*q2_[j+0]; oB += S2[j+1]*q2_[j+1];                          \
      oC += S2[j+2]*q2_[j+2]; oD += S2[j+3]*q2_[j+3]; }                        \
    f32x2 oo = (oA+oB)+(oC+oD);                                                \
    Of[S][lane] = oo.x + oo.y;                                                 \
  } while(0)

  #define COMBINE(BUF,T0) do {                                                 \
    _Pragma("unroll")                                                          \
    for (int i=0;i<16;i++){                                                    \
      int idx = i*64 + lane;                                                   \
      int s_ = idx >> 5, c_ = idx & 31;                                        \
      float fv = Of[s_][c_];                                                   \
      float sv = Of[s_][c_+32];                                                \
      float gv = Bg[BUF][1][s_];                                               \
      qb[(size_t)((T0)+s_)*LDX + c_] = (f16)(gv*fv + (1.0f-gv)*sv);            \
    }                                                                          \
  } while(0)

  LOADG(0);
  STAGE(0);
  __syncthreads();

  float4 kA[8], qA[8], kB[8], qB[8];
  float vA, bA, vB, bB;

  for (int tile=0; tile<SS/TB; tile++){
    int buf = tile & 1;
    if (tile < SS/TB-1) LOADG((tile+1)*TB);
    LDSTEP(buf, 0, kA, qA, vA, bA);
    #pragma unroll
    for (int s=0; s<TB; s+=2){
      if (s+1 < TB) LDSTEP(buf, s+1, kB, qB, vB, bB);
      STEP(kA, qA, vA, bA, s);
      if (s+2 < TB) LDSTEP(buf, s+2, kA, qA, vA, bA);
      STEP(kB, qB, vB, bB, s+1);
    }
    if (tile < SS/TB-1) STAGE(1-buf);
    COMBINE(buf, tile*TB);
    __syncthreads();
  }
  #undef LOADG
  #undef STAGE
  #undef LDSTEP
  #undef STEP
  #undef COMBINE
}

// ---------------- masked mean-pool + L2 normalize ----------------
__global__ __launch_bounds__(384) void pool_kernel(
    const float* __restrict__ x, const int* __restrict__ mask, float* __restrict__ out)
{
  __shared__ float red[384];
  __shared__ float tot;
  int b = blockIdx.x, d = threadIdx.x;
  const float* xb = x + (size_t)b*SS*DD;
  const int* mb = mask + b*SS;
  float s=0.f, sm=0.f;
  for (int t=0;t<SS;t++){ float m=(float)mb[t]; s += xb[(size_t)t*DD+d]*m; sm += m; }
  float emb = s / fmaxf(sm, 1e-9f);
  red[d] = emb*emb;
  __syncthreads();
  for (int off=192; off>=3; off>>=1){
    if (d < off) red[d] += red[d+off];
    __syncthreads();
  }
  if (d==0) tot = red[0]+red[1]+red[2];
  __syncthreads();
  out[(size_t)b*DD + d] = emb * rsqrtf(tot);
}

extern "C" void kernel_launch(void* const* d_in, const int* in_sizes, int n_in,
                              void* d_out, int out_size, void* d_ws, size_t ws_size,
                              hipStream_t stream)
{
  const int*   ids  = (const int*)d_in[0];
  const int*   amask= (const int*)d_in[1];
  const float* we   = (const float*)d_in[2];
  const float* pe   = (const float*)d_in[3];
  const float* te   = (const float*)d_in[4];
  const float* elnw = (const float*)d_in[5];
  const float* elnb = (const float*)d_in[6];
  const float* Wq   = (const float*)d_in[7];
  const float* bq   = (const float*)d_in[8];
  const float* Wk   = (const float*)d_in[9];
  const float* bk   = (const float*)d_in[10];
  const float* Wv   = (const float*)d_in[11];
  const float* bv   = (const float*)d_in[12];
  const float* Wb   = (const float*)d_in[13];
  const float* bb   = (const float*)d_in[14];
  const float* Wg   = (const float*)d_in[15];
  const float* bgp  = (const float*)d_in[16];
  const float* Wo   = (const float*)d_in[17];
  const float* bo   = (const float*)d_in[18];
  const float* fl   = (const float*)d_in[19];
  const float* sl   = (const float*)d_in[20];
  const float* alnw = (const float*)d_in[21];
  const float* alnb = (const float*)d_in[22];
  const float* W1   = (const float*)d_in[23];
  const float* b1   = (const float*)d_in[24];
  const float* W2   = (const float*)d_in[25];
  const float* b2   = (const float*)d_in[26];
  const float* flnw = (const float*)d_in[27];
  const float* flnb = (const float*)d_in[28];
  float* out = (float*)d_out;
  float* w = (float*)d_ws;

  // workspace (float slots), total 49,355,520 f = 197.4 MB
  // x    [0, 12.58M f)           : residual f32
  // xh   [12.58M, 18.87M f)      : x as f16; FFN2 f16 output reuses this buffer
  // qkvh [18.87M, 37.75M f)      : qkv rows [32768][1152] f16
  // f2   [37.75M, 44.04M f)      : tail of full-M hidden; beta/gbuf live here.
  //   Lifetime: beta(l)/g(l) written by ffn-add_ln(l-1) (or embed_ln for l=0),
  //   consumed by scan(l) (QKV(l) touches qkvh only), clobbered by FFN1(l) after.
  // wt   [44.04M, 49.35M f)      : transposed f16 weights (6 layers)
  float* x    = w;                      // 12,582,912 f
  f16*  xh   = (f16*)(w + 12582912);    // 12,582,912 h
  f16*  qkvh = (f16*)(w + 18874368);    // 37,748,736 h  [row][1152]
  float* f2   = w + 37748736;           //  6,291,456 f region
  float* beta = f2 + 3145728;           //    393,216 f
  float* gbuf = beta + 393216;          //    393,216 f
  f16*  wt   = (f16*)(w + 44040192);    // 10,616,832 h (all 6 layers)
  float* bqkv = w + 49348608;           //      6,912 f
  f16*  hb   = qkvh;                    // full-M FFN hidden [32768][1536] h (overlays qkvh+f2)

  const size_t BGLDS = 384*25*sizeof(float);   // 38400 B dynamic LDS for fused betag

  embed_ln_kernel<<<MROWS/4, 256, BGLDS, stream>>>(ids, we, pe, te, elnw, elnb, x, xh,
                                                   Wb, bb, Wg, bgp, amask, beta, gbuf);
  biaspack_kernel<<<27,256,0,stream>>>(bq, bk, bv, bqkv);
  wtrans_kernel<<<LL*1728,256,0,stream>>>(Wq, Wk, Wv, Wo, W1, W2, wt);

  for (int l=0;l<LL;l++){
    f16* wl = wt + (size_t)l*1769472;

    // fused QKV: [32768 x 1152] = xh @ [Wq|Wk|Wv]^T
    gemm_f16<0,1><<<dim3(9,256),256,0,stream>>>(xh, wl, bqkv + l*LDX, nullptr, qkvh,
                                                MROWS, LDX, DD, DD, LDX);

    // beta/g for this layer were computed by the previous layer's ffn-add_ln (or embed_ln)
    scan_kernel<<<BB*HH,64,0,stream>>>(qkvh, beta, gbuf, fl + l*HH, sl + l*HH);

    // o-proj full-M: A = attn-out = qkv[:,0:384] (lda=1152), C(f16) -> dead k-slot qkv[:,384:768]
    gemm_f16<0,1><<<dim3(3,256),256,0,stream>>>(qkvh, wl+442368, bo+l*DD, nullptr,
                                                qkvh + 384, MROWS, DD, DD, LDX, LDX);
    add_ln_kernel<1,0,1><<<MROWS/4,256,0,stream>>>(x, xh, qkvh + 384, alnw+l*DD, alnb+l*DD, 0, LDX,
                                                   nullptr, nullptr, nullptr, nullptr,
                                                   nullptr, nullptr, nullptr);

    // FFN full-M (hidden overlays qkvh+f2 exactly; qkv dead after add_ln above).
    gemm_f16<1,1><<<dim3(12,256),256,0,stream>>>(xh, wl+589824, b1+l*FFF, nullptr, hb,
                                                 MROWS, FFF, DD, DD, FFF);
    gemm_f16<0,1><<<dim3(3,256),256,0,stream>>>(hb, wl+1179648, b2+l*DD, nullptr, xh,
                                                MROWS, DD, FFF, FFF, DD);
    // ffn add_ln; for l<5 fuse betag of layer l+1 (x rows are live in registers here)
    if (l < LL-1)
      add_ln_kernel<1,1,1><<<MROWS/4,256,BGLDS,stream>>>(x, xh, xh, flnw+l*DD, flnb+l*DD, 0, DD,
                                                         Wb + (size_t)(l+1)*DD*HH, bb + (l+1)*HH,
                                                         Wg + (size_t)(l+1)*DD*HH, bgp + (l+1)*HH,
                                                         amask, beta, gbuf);
    else
      add_ln_kernel<1,0,0><<<MROWS/4,256,0,stream>>>(x, xh, xh, flnw+l*DD, flnb+l*DD, 0, DD,
                                                     nullptr, nullptr, nullptr, nullptr,
                                                     nullptr, nullptr, nullptr);
  }

  pool_kernel<<<BB,384,0,stream>>>(x, amask, out);
}